// Round 6
// baseline (1711.083 us; speedup 1.0000x reference)
//
#include <hip/hip_runtime.h>
#include <hip/hip_cooperative_groups.h>

namespace cg = cooperative_groups;

#define N_NODES 10000
#define N_EDGES 160000
#define NUM_FEAT 14
#define DIM 64
#define HID 128
#define LAYERS 28

#define NBLOCKS 250
#define TPB 1024
#define NPB 40            // nodes per block
#define GW_TOT (NBLOCKS * 16)  // 4000 waves

#define NEG_INF (-__builtin_inff())

// async global->LDS, 16B per lane: gsrc is per-lane (base + lane*4 floats),
// lds_base is wave-uniform; HW writes lds_base + lane*16.
__device__ __forceinline__ void stage16(const float* gsrc, float* lds_base) {
  __builtin_amdgcn_global_load_lds(
      (const __attribute__((address_space(1))) void*)gsrc,
      (__attribute__((address_space(3))) void*)lds_base, 16, 0, 0);
}

template <bool GUARD>
__device__ __forceinline__ void agg8(
    const int* __restrict__ src_s, const float4* __restrict__ eattr_s,
    const float* uin, int base, int rem, int lane,
    float be, float we0, float we1, float we2, float we3, float tv,
    float& m, float& sum, float& acc) {
  float msg[8], lg[8];
#pragma unroll
  for (int j = 0; j < 8; j++) {
    if (!GUARD || j < rem) {
      int sn = src_s[base + j];
      float4 ev = eattr_s[base + j];
      float mv = fmaxf(uin[(sn << 6) + lane] + be + ev.x * we0 + ev.y * we1 +
                       ev.z * we2 + ev.w * we3, 0.f) + 1e-7f;
      msg[j] = mv;
      lg[j] = mv * tv;
    } else {
      msg[j] = 0.f;
      lg[j] = NEG_INF;
    }
  }
  float t4[4];
#pragma unroll
  for (int j = 0; j < 4; j++) t4[j] = fmaxf(lg[j], lg[j + 4]);
  float bm = fmaxf(fmaxf(t4[0], t4[1]), fmaxf(t4[2], t4[3]));
  float es[8];
#pragma unroll
  for (int j = 0; j < 8; j++) es[j] = __expf(lg[j] - bm);
  float ss[4], aa[4];
#pragma unroll
  for (int j = 0; j < 4; j++) {
    ss[j] = es[j] + es[j + 4];
    aa[j] = es[j] * msg[j] + es[j + 4] * msg[j + 4];
  }
  float sB = (ss[0] + ss[1]) + (ss[2] + ss[3]);
  float aB = (aa[0] + aa[1]) + (aa[2] + aa[3]);
  float mn = fmaxf(m, bm);
  float sc = __expf(m - mn), sb = __expf(bm - mn);
  sum = sum * sc + sB * sb;
  acc = acc * sc + aB * sb;
  m = mn;
}

__global__ __launch_bounds__(1024) void k_all(
    const float* __restrict__ x, const float4* __restrict__ eattr,
    const int* __restrict__ src, const int* __restrict__ dst,
    const float* __restrict__ W_node, const float* __restrict__ b_node,
    const float* __restrict__ W_edge, const float* __restrict__ b_edge,
    const float* __restrict__ t,
    const float* __restrict__ W1a, const float* __restrict__ b1a,
    const float* __restrict__ g1a, const float* __restrict__ be1a,
    const float* __restrict__ W2a, const float* __restrict__ b2a,
    const float* __restrict__ ln_g, const float* __restrict__ ln_b,
    const float* __restrict__ W_out, const float* __restrict__ b_out,
    float* __restrict__ out,
    float* uA, float* uB, float* hc,
    int* off, int* cur, int* eids, int* src_s, float4* eattr_s) {
  cg::grid_group grid = cg::this_grid();

  __shared__ float sW1[64 * 128];   // 32 KB
  __shared__ float sW2[128 * 64];   // 32 KB
  __shared__ float sWo[64 * 64];    // 16 KB
  __shared__ float sHT[64][44];     // 11 KB  h[k][node], pad 44 (16B-aligned rows)
  __shared__ float sZT[128][44];    // 22 KB  z[j][node]

  const int tid = threadIdx.x;
  const int lane = tid & 63;
  const int wv = tid >> 6;            // 0..15
  const int bid = blockIdx.x;
  const int gt = bid * TPB + tid;     // 0..255999
  const int gw = bid * 16 + wv;       // 0..3999
  const int nbase = bid * NPB;

  // ================= CSR build =================
  if (gt < N_NODES) cur[gt] = 0;
  grid.sync();

  if (gt < N_EDGES) atomicAdd(&cur[dst[gt]], 1);
  grid.sync();

  if (bid == 0) {  // exclusive scan, block 0
    int* part = (int*)sW1;
    int base = tid * 10;
    int s = 0;
#pragma unroll
    for (int i = 0; i < 10; i++) {
      int idx = base + i;
      if (idx < N_NODES) s += cur[idx];
    }
    part[tid] = s;
    __syncthreads();
    for (int ofs = 1; ofs < 1024; ofs <<= 1) {
      int tmp = (tid >= ofs) ? part[tid - ofs] : 0;
      __syncthreads();
      part[tid] += tmp;
      __syncthreads();
    }
    int run = part[tid] - s;
#pragma unroll
    for (int i = 0; i < 10; i++) {
      int idx = base + i;
      if (idx < N_NODES) {
        int d = cur[idx];
        off[idx] = run;
        cur[idx] = run;
        run += d;
      }
    }
    if (tid == 1023) off[N_NODES] = part[1023];
  }
  grid.sync();

  if (gt < N_EDGES) {
    int p = atomicAdd(&cur[dst[gt]], 1);
    eids[p] = gt;
  }
  grid.sync();

  // sort each node's edge list by edge id (deterministic), gather src/eattr
  for (int node = gw; node < N_NODES; node += GW_TOT) {
    int a = off[node], d = off[node + 1] - a;
    if (d <= 64) {
      int key = (lane < d) ? eids[a + lane] : 0x7fffffff;
#pragma unroll
      for (int k = 2; k <= 64; k <<= 1) {
        for (int j = k >> 1; j > 0; j >>= 1) {
          int p = __shfl_xor(key, j);
          bool dirUp = ((lane & k) == 0);
          bool isLower = ((lane & j) == 0);
          key = ((isLower == dirUp) ? min(key, p) : max(key, p));
        }
      }
      if (lane < d) {
        int e = key;
        src_s[a + lane] = src[e];
        eattr_s[a + lane] = eattr[e];
      }
    } else {
      for (int i = lane; i < d; i += 64) {
        int e = eids[a + i];
        int r = 0;
        for (int j = 0; j < d; j++) r += (eids[a + j] < e) ? 1 : 0;
        src_s[a + r] = src[e];
        eattr_s[a + r] = eattr[e];
      }
    }
  }
  grid.sync();

  // ================= node encoder (own 40 nodes) =================
  for (int i = tid; i < NPB * 64; i += TPB) {
    int nl = i >> 6, k = i & 63;
    int n = nbase + nl;
    float acc = b_node[k];
#pragma unroll
    for (int f = 0; f < NUM_FEAT; f++) acc += x[n * NUM_FEAT + f] * W_node[f * 64 + k];
    hc[n * 64 + k] = acc;
    uA[n * 64 + k] = acc;
  }
  grid.sync();

  // hoisted edge-weight registers (constant across layers)
  const float we0 = W_edge[lane], we1 = W_edge[64 + lane],
              we2 = W_edge[128 + lane], we3 = W_edge[192 + lane];
  const float be = b_edge[lane];

  // ================= layers =================
  for (int l = 0; l < LAYERS; l++) {
    const float* uin = (l & 1) ? uB : uA;
    float* uout = (l & 1) ? uA : uB;
    const float* W1 = W1a + (size_t)l * 64 * 128;
    const float* W2 = W2a + (size_t)l * 128 * 64;
    const float* b1 = b1a + (size_t)l * 128;
    const float* g1 = g1a + (size_t)l * 128;
    const float* be1 = be1a + (size_t)l * 128;
    const float* b2 = b2a + (size_t)l * 64;

    // --- async weight staging (drains at the __syncthreads below) ---
    // wave wv stages floats [wv*512, wv*512+512) of W1 and W2 (2 rounds of 1KB)
    {
      int fo = wv * 512 + lane * 4;
      stage16(W1 + fo, sW1 + wv * 512);
      stage16(W1 + fo + 256, sW1 + wv * 512 + 256);
      stage16(W2 + fo, sW2 + wv * 512);
      stage16(W2 + fo + 256, sW2 + wv * 512 + 256);
      if (l == LAYERS - 1) {  // W_out: 16KB, 1KB per wave
        stage16(W_out + wv * 256 + lane * 4, sWo + wv * 256);
      }
    }

    // --- edge aggregation: own nodes nl = wv + 16*i, lane = feature ---
    {
      float tv = t[l];
      for (int nl = wv; nl < NPB; nl += 16) {
        int gn = nbase + nl;
        int a = off[gn], d = off[gn + 1] - a;
        float un = uin[(gn << 6) + lane];
        float m = NEG_INF, sum = 0.f, acc = 0.f;
        int nfull = d & ~7;
        for (int i = 0; i < nfull; i += 8)
          agg8<false>(src_s, eattr_s, uin, a + i, 8, lane, be, we0, we1, we2, we3, tv,
                      m, sum, acc);
        int rem = d - nfull;
        if (rem)
          agg8<true>(src_s, eattr_s, uin, a + nfull, rem, lane, be, we0, we1, we2, we3, tv,
                     m, sum, acc);
        sHT[lane][nl] = acc / (sum + 1e-16f) + un;  // h = agg + x
      }
    }
    __syncthreads();  // sHT (cross-wave) + staged weights ready

    // --- MLP: waves 0..9, 4-node group each; W read once per group ---
    if (wv < 10) {
      const int n0 = wv * 4;
      const int j0 = 2 * lane;

      // GEMM1: acc[4 nodes][2 cols]
      float2 b1v = *((const float2*)&b1[j0]);
      float ac[4][2];
#pragma unroll
      for (int q = 0; q < 4; q++) { ac[q][0] = b1v.x; ac[q][1] = b1v.y; }
#pragma unroll 8
      for (int k = 0; k < 64; k++) {
        float4 hv = *((float4*)&sHT[k][n0]);        // broadcast
        float2 wp = *((float2*)&sW1[k * 128 + j0]); // conflict-free b64
        ac[0][0] += hv.x * wp.x; ac[0][1] += hv.x * wp.y;
        ac[1][0] += hv.y * wp.x; ac[1][1] += hv.y * wp.y;
        ac[2][0] += hv.z * wp.x; ac[2][1] += hv.z * wp.y;
        ac[3][0] += hv.w * wp.x; ac[3][1] += hv.w * wp.y;
      }

      // LN1 over 128 (shfl reduce), relu, z -> sZT (own columns)
      {
        float2 gv = *((const float2*)&g1[j0]);
        float2 bev = *((const float2*)&be1[j0]);
        float4 zlo, zhi;
        float* zl = &zlo.x;
        float* zh = &zhi.x;
#pragma unroll
        for (int q = 0; q < 4; q++) {
          float s = ac[q][0] + ac[q][1];
          float sq = ac[q][0] * ac[q][0] + ac[q][1] * ac[q][1];
#pragma unroll
          for (int o = 32; o; o >>= 1) { s += __shfl_xor(s, o); sq += __shfl_xor(sq, o); }
          float mu = s * (1.f / 128.f);
          float rs = rsqrtf(sq * (1.f / 128.f) - mu * mu + 1e-5f);
          zl[q] = fmaxf((ac[q][0] - mu) * rs * gv.x + bev.x, 0.f);
          zh[q] = fmaxf((ac[q][1] - mu) * rs * gv.y + bev.y, 0.f);
        }
        *((float4*)&sZT[j0][n0]) = zlo;
        *((float4*)&sZT[j0 + 1][n0]) = zhi;  // within-wave; read below by same wave
      }

      // GEMM2: o[4 nodes], col = lane
      float o4[4];
      {
        float bo = b2[lane];
        o4[0] = bo; o4[1] = bo; o4[2] = bo; o4[3] = bo;
      }
#pragma unroll 8
      for (int k = 0; k < 128; k++) {
        float4 zv = *((float4*)&sZT[k][n0]);  // broadcast
        float w = sW2[k * 64 + lane];         // conflict-free b32
        o4[0] += zv.x * w;
        o4[1] += zv.y * w;
        o4[2] += zv.z * w;
        o4[3] += zv.w * w;
      }

      // residual + hc write
      float hcn[4];
#pragma unroll
      for (int q = 0; q < 4; q++) {
        int gn = nbase + n0 + q;
        float r = (l > 0) ? hc[gn * 64 + lane] : 0.f;
        hcn[q] = o4[q] + r;
        hc[gn * 64 + lane] = hcn[q];
      }

      if (l < LAYERS - 1) {
        // next-layer pre-LN: uout = relu(LN(hc, ln_g[l+1], ln_b[l+1]))
        float lg_ = ln_g[(l + 1) * 64 + lane], lb_ = ln_b[(l + 1) * 64 + lane];
#pragma unroll
        for (int q = 0; q < 4; q++) {
          float s = hcn[q], sq = hcn[q] * hcn[q];
#pragma unroll
          for (int o = 32; o; o >>= 1) { s += __shfl_xor(s, o); sq += __shfl_xor(sq, o); }
          float mu = s * (1.f / 64.f);
          float rs = rsqrtf(sq * (1.f / 64.f) - mu * mu + 1e-5f);
          uout[(nbase + n0 + q) * 64 + lane] = fmaxf((hcn[q] - mu) * rs * lg_ + lb_, 0.f);
        }
      } else {
        // final: z = relu(LN(hc, ln_g[0], ln_b[0])); out = z @ W_out + b_out
        float lg_ = ln_g[lane], lb_ = ln_b[lane];
        float zf[4];
#pragma unroll
        for (int q = 0; q < 4; q++) {
          float s = hcn[q], sq = hcn[q] * hcn[q];
#pragma unroll
          for (int o = 32; o; o >>= 1) { s += __shfl_xor(s, o); sq += __shfl_xor(sq, o); }
          float mu = s * (1.f / 64.f);
          float rs = rsqrtf(sq * (1.f / 64.f) - mu * mu + 1e-5f);
          zf[q] = fmaxf((hcn[q] - mu) * rs * lg_ + lb_, 0.f);
          sHT[lane][n0 + q] = zf[q];  // own columns; same-wave DS ordering
        }
        float oo[4];
        {
          float bo = b_out[lane];
          oo[0] = bo; oo[1] = bo; oo[2] = bo; oo[3] = bo;
        }
#pragma unroll 8
        for (int k = 0; k < 64; k++) {
          float4 zv = *((float4*)&sHT[k][n0]);  // broadcast (own cols, own wave)
          float w = sWo[k * 64 + lane];
          oo[0] += zv.x * w;
          oo[1] += zv.y * w;
          oo[2] += zv.z * w;
          oo[3] += zv.w * w;
        }
#pragma unroll
        for (int q = 0; q < 4; q++) out[(nbase + n0 + q) * 64 + lane] = oo[q];
      }
    }

    if (l < LAYERS - 1) grid.sync();  // uout visible device-wide for next layer
  }
}

// ---------------- host ----------------

extern "C" void kernel_launch(void* const* d_in, const int* in_sizes, int n_in,
                              void* d_out, int out_size, void* d_ws, size_t ws_size,
                              hipStream_t stream) {
  const float* x        = (const float*)d_in[0];
  const float4* eattr   = (const float4*)d_in[1];
  const int*   src      = (const int*)d_in[2];
  const int*   dst      = (const int*)d_in[3];
  const float* W_node   = (const float*)d_in[4];
  const float* b_node   = (const float*)d_in[5];
  const float* W_edge   = (const float*)d_in[6];
  const float* b_edge   = (const float*)d_in[7];
  const float* t        = (const float*)d_in[8];
  const float* W1       = (const float*)d_in[9];
  const float* b1       = (const float*)d_in[10];
  const float* g1       = (const float*)d_in[11];
  const float* be1      = (const float*)d_in[12];
  const float* W2       = (const float*)d_in[13];
  const float* b2       = (const float*)d_in[14];
  const float* ln_g     = (const float*)d_in[15];
  const float* ln_b     = (const float*)d_in[16];
  const float* W_out    = (const float*)d_in[17];
  const float* b_out    = (const float*)d_in[18];
  float* out = (float*)d_out;

  char* w = (char*)d_ws;
  float* uA       = (float*)w;  w += (size_t)N_NODES * 64 * 4;
  float* uB       = (float*)w;  w += (size_t)N_NODES * 64 * 4;
  float* hcb      = (float*)w;  w += (size_t)N_NODES * 64 * 4;
  int* off        = (int*)w;    w += (size_t)(N_NODES + 1) * 4;
  int* cur        = (int*)w;    w += (size_t)N_NODES * 4;
  int* eids       = (int*)w;    w += (size_t)N_EDGES * 4;
  int* src_s      = (int*)w;    w += (size_t)N_EDGES * 4;
  float4* eattr_s = (float4*)w; w += (size_t)N_EDGES * 16;

  void* args[] = {
      (void*)&x, (void*)&eattr, (void*)&src, (void*)&dst,
      (void*)&W_node, (void*)&b_node, (void*)&W_edge, (void*)&b_edge, (void*)&t,
      (void*)&W1, (void*)&b1, (void*)&g1, (void*)&be1, (void*)&W2, (void*)&b2,
      (void*)&ln_g, (void*)&ln_b, (void*)&W_out, (void*)&b_out,
      (void*)&out, (void*)&uA, (void*)&uB, (void*)&hcb,
      (void*)&off, (void*)&cur, (void*)&eids, (void*)&src_s, (void*)&eattr_s};

  hipLaunchCooperativeKernel((const void*)k_all, dim3(NBLOCKS), dim3(TPB),
                             args, 0, stream);
}

// Round 7
// 1294.174 us; speedup vs baseline: 1.3221x; 1.3221x over previous
//
#include <hip/hip_runtime.h>

#define N_NODES 10000
#define N_EDGES 160000
#define NUM_FEAT 14
#define EDGE_DIM 4
#define DIM 64
#define HID 128
#define LAYERS 28

#define NEG_INF (-__builtin_inff())

// ---------------- CSR build ----------------

__global__ __launch_bounds__(256) void k_zero(int* __restrict__ p, int n) {
  int i = blockIdx.x * 256 + threadIdx.x;
  if (i < n) p[i] = 0;
}

__global__ __launch_bounds__(256) void k_hist(const int* __restrict__ dst, int* __restrict__ cur) {
  int e = blockIdx.x * 256 + threadIdx.x;
  if (e < N_EDGES) atomicAdd(&cur[dst[e]], 1);
}

__global__ __launch_bounds__(256) void k_scan(int* __restrict__ cur, int* __restrict__ off) {
  __shared__ int part[256];
  int t = threadIdx.x;
  const int CH = 40;
  int base = t * CH;
  int s = 0;
  for (int i = 0; i < CH; i++) {
    int idx = base + i;
    if (idx < N_NODES) s += cur[idx];
  }
  part[t] = s;
  __syncthreads();
  for (int ofs = 1; ofs < 256; ofs <<= 1) {
    int tmp = (t >= ofs) ? part[t - ofs] : 0;
    __syncthreads();
    part[t] += tmp;
    __syncthreads();
  }
  int run = part[t] - s;
  for (int i = 0; i < CH; i++) {
    int idx = base + i;
    if (idx < N_NODES) {
      int d = cur[idx];
      off[idx] = run;
      cur[idx] = run;
      run += d;
    }
  }
  if (t == 255) off[N_NODES] = part[255];
}

__global__ __launch_bounds__(256) void k_scatter(const int* __restrict__ dst, int* __restrict__ cur,
                                                 int* __restrict__ eids) {
  int e = blockIdx.x * 256 + threadIdx.x;
  if (e < N_EDGES) {
    int p = atomicAdd(&cur[dst[e]], 1);
    eids[p] = e;
  }
}

// wave-per-node bitonic sort of edge ids, then gather src/eattr into slot order.
__global__ __launch_bounds__(256) void k_sortgather(
    const int* __restrict__ off, const int* __restrict__ eids,
    const int* __restrict__ src, const float4* __restrict__ eattr,
    int* __restrict__ src_s, float4* __restrict__ eattr_s) {
  int node = blockIdx.x * 4 + (threadIdx.x >> 6);
  int lane = threadIdx.x & 63;
  if (node >= N_NODES) return;
  int a = off[node];
  int d = off[node + 1] - a;
  if (d <= 64) {
    int key = (lane < d) ? eids[a + lane] : 0x7fffffff;
#pragma unroll
    for (int k = 2; k <= 64; k <<= 1) {
      for (int j = k >> 1; j > 0; j >>= 1) {
        int p = __shfl_xor(key, j);
        bool dirUp = ((lane & k) == 0);
        bool isLower = ((lane & j) == 0);
        key = ((isLower == dirUp) ? min(key, p) : max(key, p));
      }
    }
    if (lane < d) {
      int e = key;
      src_s[a + lane] = src[e];
      eattr_s[a + lane] = eattr[e];
    }
  } else {
    for (int i = lane; i < d; i += 64) {
      int e = eids[a + i];
      int r = 0;
      for (int j = 0; j < d; j++) r += (eids[a + j] < e) ? 1 : 0;
      src_s[a + r] = src[e];
      eattr_s[a + r] = eattr[e];
    }
  }
}

// ---------------- node encoder ----------------

__global__ __launch_bounds__(256) void k_enc(const float* __restrict__ x, const float* __restrict__ Wn,
                                             const float* __restrict__ bn, float* __restrict__ hc,
                                             float* __restrict__ u) {
  int gid = blockIdx.x * 256 + threadIdx.x;
  if (gid >= N_NODES * DIM) return;
  int n = gid >> 6, j = gid & 63;
  float acc = bn[j];
#pragma unroll
  for (int k = 0; k < NUM_FEAT; k++) acc += x[n * NUM_FEAT + k] * Wn[k * DIM + j];
  hc[gid] = acc;
  u[gid] = acc;
}

// ---------------- edge aggregation: 1 node/wave, batch-16 tree softmax ----------------

template <bool GUARD>
__device__ __forceinline__ void agg_batch(
    const int* __restrict__ src_s, const float4* __restrict__ eattr_s,
    const float* __restrict__ uin, int base, int rem, int lane,
    float be, float we0, float we1, float we2, float we3, float tv,
    float& m, float& sum, float& acc) {
  float msg[16], lg[16];
#pragma unroll
  for (int j = 0; j < 16; j++) {
    if (!GUARD || j < rem) {
      int sn = src_s[base + j];
      float4 ev = eattr_s[base + j];
      float mv = fmaxf(uin[(sn << 6) + lane] + be + ev.x * we0 + ev.y * we1 +
                       ev.z * we2 + ev.w * we3, 0.f) + 1e-7f;
      msg[j] = mv;
      lg[j] = mv * tv;
    } else {
      msg[j] = 0.f;
      lg[j] = NEG_INF;
    }
  }
  float t8[8];
#pragma unroll
  for (int j = 0; j < 8; j++) t8[j] = fmaxf(lg[j], lg[j + 8]);
#pragma unroll
  for (int j = 0; j < 4; j++) t8[j] = fmaxf(t8[j], t8[j + 4]);
  float bm = fmaxf(fmaxf(t8[0], t8[2]), fmaxf(t8[1], t8[3]));
  float es[16];
#pragma unroll
  for (int j = 0; j < 16; j++) es[j] = __expf(lg[j] - bm);
  float ss[8], aa[8];
#pragma unroll
  for (int j = 0; j < 8; j++) {
    ss[j] = es[j] + es[j + 8];
    aa[j] = es[j] * msg[j] + es[j + 8] * msg[j + 8];
  }
#pragma unroll
  for (int j = 0; j < 4; j++) { ss[j] += ss[j + 4]; aa[j] += aa[j + 4]; }
  float sB = (ss[0] + ss[2]) + (ss[1] + ss[3]);
  float aB = (aa[0] + aa[2]) + (aa[1] + aa[3]);
  float mn = fmaxf(m, bm);
  float sc = __expf(m - mn), sb = __expf(bm - mn);
  sum = sum * sc + sB * sb;
  acc = acc * sc + aB * sb;
  m = mn;
}

__global__ __launch_bounds__(256) void k_edge(
    const float* __restrict__ uin, const float4* __restrict__ eattr_s,
    const int* __restrict__ src_s,
    const float* __restrict__ W_edge, const float* __restrict__ b_edge,
    const int* __restrict__ off,
    const float* __restrict__ tptr, int layer, float* __restrict__ htmp) {
  int node = (blockIdx.x << 2) + (threadIdx.x >> 6);
  int lane = threadIdx.x & 63;
  if (node >= N_NODES) return;
  float tv = tptr[layer];
  float we0 = W_edge[lane], we1 = W_edge[64 + lane], we2 = W_edge[128 + lane],
        we3 = W_edge[192 + lane];
  float be = b_edge[lane];
  int a = off[node], d = off[node + 1] - a;
  float un = uin[(node << 6) + lane];
  float m = NEG_INF, sum = 0.f, acc = 0.f;
  int nfull = d & ~15;
  for (int i = 0; i < nfull; i += 16)
    agg_batch<false>(src_s, eattr_s, uin, a + i, 16, lane, be, we0, we1, we2, we3, tv,
                     m, sum, acc);
  int rem = d - nfull;
  if (rem)
    agg_batch<true>(src_s, eattr_s, uin, a + nfull, rem, lane, be, we0, we1, we2, we3, tv,
                    m, sum, acc);
  htmp[(node << 6) + lane] = acc / (sum + 1e-16f) + un;
}

// ---------------- MLP: scalar-W GEMM, lane = node ----------------
// 512 threads (8 waves), 64 nodes/block, grid 157. Wave wv owns a column slice
// (16 cols in GEMM1, 8 in GEMM2); W elements are wave-uniform -> s_load from
// global (scalar cache), ZERO LDS traffic for weights. Per-lane operand h/z is
// one conflict-free 4B ds_read feeding 16/8 FMAs. LN partial-reduced via LDS.

#define MGRID ((N_NODES + 63) / 64)  // 157

__global__ __launch_bounds__(512) void k_mlp3(
    const float* __restrict__ hin, float* __restrict__ hc, float* __restrict__ uout,
    const float* __restrict__ W1, const float* __restrict__ b1,
    const float* __restrict__ g1, const float* __restrict__ be1,
    const float* __restrict__ W2, const float* __restrict__ b2,
    const float* __restrict__ lng, const float* __restrict__ lnb,
    int addRes, int writeU) {
  __shared__ float sH[64][65];    // h tile [k][n], +1 pad: conflict-free both ways
  __shared__ float sZ[128][65];   // z tile [j][n]
  __shared__ float sP[8 * 130];   // LN partials: (s,sq) float2 per (wave, node)

  const int tid = threadIdx.x;
  const int lane = tid & 63;
  const int wvu = __builtin_amdgcn_readfirstlane(tid >> 6);  // SGPR wave id
  const int n0 = blockIdx.x * 64;
  const bool ok = (n0 + lane) < N_NODES;
  const int gn = n0 + lane;

  // load h tile (coalesced in k; LDS writes conflict-free via +1 pad)
  for (int idx = tid; idx < 4096; idx += 512) {
    int n = idx >> 6, k = idx & 63;
    sH[k][n] = (n0 + n < N_NODES) ? hin[(n0 + n) * 64 + k] : 0.f;
  }
  __syncthreads();

  // ---- GEMM1: wave owns cols j0..j0+15; W1 via s_load ----
  const int j0 = wvu * 16;
  float acc[16];
#pragma unroll
  for (int c = 0; c < 16; c++) acc[c] = b1[j0 + c];
#pragma unroll 4
  for (int k = 0; k < 64; k++) {
    float h = sH[k][lane];
#pragma unroll
    for (int c = 0; c < 16; c++) acc[c] = fmaf(h, W1[k * 128 + j0 + c], acc[c]);
  }

  // ---- LN1 over 128 (8-wave partial reduce) ----
  {
    float s = 0.f, sq = 0.f;
#pragma unroll
    for (int c = 0; c < 16; c++) { s += acc[c]; sq += acc[c] * acc[c]; }
    *((float2*)&sP[wvu * 130 + lane * 2]) = make_float2(s, sq);
  }
  __syncthreads();
  {
    float s = 0.f, sq = 0.f;
#pragma unroll
    for (int w = 0; w < 8; w++) {
      float2 p = *((float2*)&sP[w * 130 + lane * 2]);
      s += p.x; sq += p.y;
    }
    float mu = s * (1.f / 128.f);
    float rs = rsqrtf(sq * (1.f / 128.f) - mu * mu + 1e-5f);
#pragma unroll
    for (int c = 0; c < 16; c++) {
      float z = fmaxf((acc[c] - mu) * rs * g1[j0 + c] + be1[j0 + c], 0.f);
      sZ[j0 + c][lane] = z;
    }
  }
  __syncthreads();  // sZ ready (also orders sP reads before LN2 writes)

  // ---- GEMM2: wave owns cols i0..i0+7; W2 via s_load ----
  const int i0 = wvu * 8;
  float o[8];
#pragma unroll
  for (int c = 0; c < 8; c++) o[c] = b2[i0 + c];
#pragma unroll 4
  for (int j = 0; j < 128; j++) {
    float z = sZ[j][lane];
#pragma unroll
    for (int c = 0; c < 8; c++) o[c] = fmaf(z, W2[j * 64 + i0 + c], o[c]);
  }

  // ---- residual + hc write ----
  float hcn[8];
  if (ok) {
    if (addRes) {
      float4 r0 = *((const float4*)&hc[gn * 64 + i0]);
      float4 r1 = *((const float4*)&hc[gn * 64 + i0 + 4]);
      hcn[0] = o[0] + r0.x; hcn[1] = o[1] + r0.y;
      hcn[2] = o[2] + r0.z; hcn[3] = o[3] + r0.w;
      hcn[4] = o[4] + r1.x; hcn[5] = o[5] + r1.y;
      hcn[6] = o[6] + r1.z; hcn[7] = o[7] + r1.w;
    } else {
#pragma unroll
      for (int c = 0; c < 8; c++) hcn[c] = o[c];
    }
    *((float4*)&hc[gn * 64 + i0]) = make_float4(hcn[0], hcn[1], hcn[2], hcn[3]);
    *((float4*)&hc[gn * 64 + i0 + 4]) = make_float4(hcn[4], hcn[5], hcn[6], hcn[7]);
  } else {
#pragma unroll
    for (int c = 0; c < 8; c++) hcn[c] = 0.f;
  }

  // ---- next-layer pre-LN: uout = relu(LN(hc)) ----
  if (writeU) {
    float s = 0.f, sq = 0.f;
#pragma unroll
    for (int c = 0; c < 8; c++) { s += hcn[c]; sq += hcn[c] * hcn[c]; }
    *((float2*)&sP[wvu * 130 + lane * 2]) = make_float2(s, sq);
    __syncthreads();
    float st = 0.f, sqt = 0.f;
#pragma unroll
    for (int w = 0; w < 8; w++) {
      float2 p = *((float2*)&sP[w * 130 + lane * 2]);
      st += p.x; sqt += p.y;
    }
    float mu = st * (1.f / 64.f);
    float rs = rsqrtf(sqt * (1.f / 64.f) - mu * mu + 1e-5f);
    if (ok) {
      float uo[8];
#pragma unroll
      for (int c = 0; c < 8; c++)
        uo[c] = fmaxf((hcn[c] - mu) * rs * lng[i0 + c] + lnb[i0 + c], 0.f);
      *((float4*)&uout[gn * 64 + i0]) = make_float4(uo[0], uo[1], uo[2], uo[3]);
      *((float4*)&uout[gn * 64 + i0 + 4]) = make_float4(uo[4], uo[5], uo[6], uo[7]);
    }
  }
}

// ---------------- final: out = relu(LN(hc, g0, b0)) @ W_out + b_out ----------------

__global__ __launch_bounds__(256) void k_final(const float* __restrict__ hc, const float* __restrict__ g,
                                               const float* __restrict__ bptr, const float* __restrict__ Wout,
                                               const float* __restrict__ bout, float* __restrict__ out) {
  __shared__ float sW[DIM * DIM];
  int tid = threadIdx.x;
  for (int i = tid; i < 1024; i += 256) ((float4*)sW)[i] = ((const float4*)Wout)[i];
  __syncthreads();
  int lane = tid & 63, w = tid >> 6;
  int n = blockIdx.x * 4 + w;
  if (n >= N_NODES) return;
  float v = hc[n * 64 + lane];
  float s = v, q = v * v;
#pragma unroll
  for (int o = 32; o; o >>= 1) { s += __shfl_xor(s, o); q += __shfl_xor(q, o); }
  float mu = s * (1.f / 64.f);
  float var = q * (1.f / 64.f) - mu * mu;
  float rs = rsqrtf(var + 1e-5f);
  float z = fmaxf((v - mu) * rs * g[lane] + bptr[lane], 0.f);
  float acc = bout[lane];
  for (int k = 0; k < 64; k++) {
    float zk = __shfl(z, k);
    acc += zk * sW[k * 64 + lane];
  }
  out[n * 64 + lane] = acc;
}

// ---------------- host ----------------

extern "C" void kernel_launch(void* const* d_in, const int* in_sizes, int n_in,
                              void* d_out, int out_size, void* d_ws, size_t ws_size,
                              hipStream_t stream) {
  const float* x        = (const float*)d_in[0];
  const float* eattr    = (const float*)d_in[1];
  const int*   src      = (const int*)d_in[2];
  const int*   dst      = (const int*)d_in[3];
  const float* W_node   = (const float*)d_in[4];
  const float* b_node   = (const float*)d_in[5];
  const float* W_edge   = (const float*)d_in[6];
  const float* b_edge   = (const float*)d_in[7];
  const float* t        = (const float*)d_in[8];
  const float* W1       = (const float*)d_in[9];
  const float* b1       = (const float*)d_in[10];
  const float* g1       = (const float*)d_in[11];
  const float* be1      = (const float*)d_in[12];
  const float* W2       = (const float*)d_in[13];
  const float* b2       = (const float*)d_in[14];
  const float* ln_g     = (const float*)d_in[15];
  const float* ln_b     = (const float*)d_in[16];
  const float* W_out    = (const float*)d_in[17];
  const float* b_out    = (const float*)d_in[18];
  float* out = (float*)d_out;

  char* w = (char*)d_ws;
  float* u       = (float*)w;  w += (size_t)N_NODES * 64 * 4;
  float* hcb     = (float*)w;  w += (size_t)N_NODES * 64 * 4;
  float* htmp    = (float*)w;  w += (size_t)N_NODES * 64 * 4;
  int* off       = (int*)w;    w += (size_t)(N_NODES + 1) * 4;
  int* cur       = (int*)w;    w += (size_t)N_NODES * 4;
  int* eids      = (int*)w;    w += (size_t)N_EDGES * 4;
  int* src_s     = (int*)w;    w += (size_t)N_EDGES * 4;
  float4* eattr_s = (float4*)w; w += (size_t)N_EDGES * 16;

  k_zero<<<(N_NODES + 255) / 256, 256, 0, stream>>>(cur, N_NODES);
  k_hist<<<(N_EDGES + 255) / 256, 256, 0, stream>>>(dst, cur);
  k_scan<<<1, 256, 0, stream>>>(cur, off);
  k_scatter<<<(N_EDGES + 255) / 256, 256, 0, stream>>>(dst, cur, eids);
  k_sortgather<<<(N_NODES + 3) / 4, 256, 0, stream>>>(off, eids, src, (const float4*)eattr,
                                                      src_s, eattr_s);

  k_enc<<<(N_NODES * 64 + 255) / 256, 256, 0, stream>>>(x, W_node, b_node, hcb, u);

  for (int l = 0; l < LAYERS; l++) {
    k_edge<<<(N_NODES + 3) / 4, 256, 0, stream>>>(u, eattr_s, src_s, W_edge, b_edge,
                                                  off, t, l, htmp);
    int nxt = (l + 1 < LAYERS) ? (l + 1) : 0;  // unused when writeU=0
    k_mlp3<<<MGRID, 512, 0, stream>>>(htmp, hcb, u,
                                      W1 + (size_t)l * DIM * HID, b1 + (size_t)l * HID,
                                      g1 + (size_t)l * HID, be1 + (size_t)l * HID,
                                      W2 + (size_t)l * HID * DIM, b2 + (size_t)l * DIM,
                                      ln_g + (size_t)nxt * DIM, ln_b + (size_t)nxt * DIM,
                                      (l > 0) ? 1 : 0, (l < LAYERS - 1) ? 1 : 0);
  }

  k_final<<<(N_NODES + 3) / 4, 256, 0, stream>>>(hcb, ln_g, ln_b, W_out, b_out, out);
}

// Round 8
// 1004.299 us; speedup vs baseline: 1.7038x; 1.2886x over previous
//
#include <hip/hip_runtime.h>

#define N_NODES 10000
#define N_EDGES 160000
#define NUM_FEAT 14
#define EDGE_DIM 4
#define DIM 64
#define HID 128
#define LAYERS 28

#define NEG_INF (-__builtin_inff())

// ---------------- CSR build ----------------

__global__ __launch_bounds__(256) void k_zero(int* __restrict__ p, int n) {
  int i = blockIdx.x * 256 + threadIdx.x;
  if (i < n) p[i] = 0;
}

__global__ __launch_bounds__(256) void k_hist(const int* __restrict__ dst, int* __restrict__ cur) {
  int e = blockIdx.x * 256 + threadIdx.x;
  if (e < N_EDGES) atomicAdd(&cur[dst[e]], 1);
}

__global__ __launch_bounds__(256) void k_scan(int* __restrict__ cur, int* __restrict__ off) {
  __shared__ int part[256];
  int t = threadIdx.x;
  const int CH = 40;
  int base = t * CH;
  int s = 0;
  for (int i = 0; i < CH; i++) {
    int idx = base + i;
    if (idx < N_NODES) s += cur[idx];
  }
  part[t] = s;
  __syncthreads();
  for (int ofs = 1; ofs < 256; ofs <<= 1) {
    int tmp = (t >= ofs) ? part[t - ofs] : 0;
    __syncthreads();
    part[t] += tmp;
    __syncthreads();
  }
  int run = part[t] - s;
  for (int i = 0; i < CH; i++) {
    int idx = base + i;
    if (idx < N_NODES) {
      int d = cur[idx];
      off[idx] = run;
      cur[idx] = run;
      run += d;
    }
  }
  if (t == 255) off[N_NODES] = part[255];
}

__global__ __launch_bounds__(256) void k_scatter(const int* __restrict__ dst, int* __restrict__ cur,
                                                 int* __restrict__ eids) {
  int e = blockIdx.x * 256 + threadIdx.x;
  if (e < N_EDGES) {
    int p = atomicAdd(&cur[dst[e]], 1);
    eids[p] = e;
  }
}

// wave-per-node bitonic sort of edge ids, then gather src/eattr into slot order.
__global__ __launch_bounds__(256) void k_sortgather(
    const int* __restrict__ off, const int* __restrict__ eids,
    const int* __restrict__ src, const float4* __restrict__ eattr,
    int* __restrict__ src_s, float4* __restrict__ eattr_s) {
  int node = blockIdx.x * 4 + (threadIdx.x >> 6);
  int lane = threadIdx.x & 63;
  if (node >= N_NODES) return;
  int a = off[node];
  int d = off[node + 1] - a;
  if (d <= 64) {
    int key = (lane < d) ? eids[a + lane] : 0x7fffffff;
#pragma unroll
    for (int k = 2; k <= 64; k <<= 1) {
      for (int j = k >> 1; j > 0; j >>= 1) {
        int p = __shfl_xor(key, j);
        bool dirUp = ((lane & k) == 0);
        bool isLower = ((lane & j) == 0);
        key = ((isLower == dirUp) ? min(key, p) : max(key, p));
      }
    }
    if (lane < d) {
      int e = key;
      src_s[a + lane] = src[e];
      eattr_s[a + lane] = eattr[e];
    }
  } else {
    for (int i = lane; i < d; i += 64) {
      int e = eids[a + i];
      int r = 0;
      for (int j = 0; j < d; j++) r += (eids[a + j] < e) ? 1 : 0;
      src_s[a + r] = src[e];
      eattr_s[a + r] = eattr[e];
    }
  }
}

// ---------------- per-slot edge embedding: ea_s[slot][f] (one-time) ----------------

__global__ __launch_bounds__(256) void k_ea(const float4* __restrict__ eattr_s,
                                            const float* __restrict__ W_edge,
                                            const float* __restrict__ b_edge,
                                            float* __restrict__ ea_s) {
  int gid = blockIdx.x * 256 + threadIdx.x;
  if (gid >= N_EDGES * 64) return;
  int slot = gid >> 6, f = gid & 63;
  float4 ev = eattr_s[slot];
  ea_s[gid] = b_edge[f] + ev.x * W_edge[f] + ev.y * W_edge[64 + f] +
              ev.z * W_edge[128 + f] + ev.w * W_edge[192 + f];
}

// ---------------- node encoder ----------------

__global__ __launch_bounds__(256) void k_enc(const float* __restrict__ x, const float* __restrict__ Wn,
                                             const float* __restrict__ bn, float* __restrict__ hc,
                                             float* __restrict__ u) {
  int gid = blockIdx.x * 256 + threadIdx.x;
  if (gid >= N_NODES * DIM) return;
  int n = gid >> 6, j = gid & 63;
  float acc = bn[j];
#pragma unroll
  for (int k = 0; k < NUM_FEAT; k++) acc += x[n * NUM_FEAT + k] * Wn[k * DIM + j];
  hc[gid] = acc;
  u[gid] = acc;
}

// ---------------- edge aggregation: 1 node/wave, batch-8, scalar metadata ----------------
// Per edge: one s_load (src id), two coalesced 256B vector loads (u row, ea row).
// Loads grouped before compute; ~50 VGPRs -> 8 waves/SIMD of latency hiding.

template <bool GUARD>
__device__ __forceinline__ void agg8(
    const int* __restrict__ src_s, const float* __restrict__ ea_s,
    const float* __restrict__ uin, int base, int rem, int lane, float tv,
    float& m, float& sum, float& acc) {
  float uv[8], ev[8];
#pragma unroll
  for (int j = 0; j < 8; j++) {
    if (!GUARD || j < rem) {
      int sn = src_s[base + j];            // scalar load (uniform addr)
      uv[j] = uin[(sn << 6) + lane];       // sgpr base + lane
      ev[j] = ea_s[((base + j) << 6) + lane];
    }
  }
  float msg[8], lg[8];
#pragma unroll
  for (int j = 0; j < 8; j++) {
    if (!GUARD || j < rem) {
      float mv = fmaxf(uv[j] + ev[j], 0.f) + 1e-7f;
      msg[j] = mv;
      lg[j] = mv * tv;
    } else {
      msg[j] = 0.f;
      lg[j] = NEG_INF;
    }
  }
  float t4[4];
#pragma unroll
  for (int j = 0; j < 4; j++) t4[j] = fmaxf(lg[j], lg[j + 4]);
  float bm = fmaxf(fmaxf(t4[0], t4[1]), fmaxf(t4[2], t4[3]));
  float es[8];
#pragma unroll
  for (int j = 0; j < 8; j++) es[j] = __expf(lg[j] - bm);
  float ss[4], aa[4];
#pragma unroll
  for (int j = 0; j < 4; j++) {
    ss[j] = es[j] + es[j + 4];
    aa[j] = es[j] * msg[j] + es[j + 4] * msg[j + 4];
  }
  float sB = (ss[0] + ss[1]) + (ss[2] + ss[3]);
  float aB = (aa[0] + aa[1]) + (aa[2] + aa[3]);
  float mn = fmaxf(m, bm);
  float sc = __expf(m - mn), sb = __expf(bm - mn);
  sum = sum * sc + sB * sb;
  acc = acc * sc + aB * sb;
  m = mn;
}

__global__ __launch_bounds__(256) void k_edge(
    const float* __restrict__ uin, const float* __restrict__ ea_s,
    const int* __restrict__ src_s, const int* __restrict__ off,
    const float* __restrict__ tptr, int layer, float* __restrict__ htmp) {
  int node = __builtin_amdgcn_readfirstlane((blockIdx.x << 2) + (threadIdx.x >> 6));
  int lane = threadIdx.x & 63;
  float tv = tptr[layer];
  int a = off[node], d = off[node + 1] - a;   // scalar
  float un = uin[(node << 6) + lane];
  float m = NEG_INF, sum = 0.f, acc = 0.f;
  int nfull = d & ~7;
  for (int i = 0; i < nfull; i += 8)
    agg8<false>(src_s, ea_s, uin, a + i, 8, lane, tv, m, sum, acc);
  int rem = d - nfull;
  if (rem)
    agg8<true>(src_s, ea_s, uin, a + nfull, rem, lane, tv, m, sum, acc);
  htmp[(node << 6) + lane] = acc / (sum + 1e-16f) + un;
}

// ---------------- MLP: 512 threads (8 waves), 2 nodes/wave, 16 nodes/block ----------------
// (R5's k_mlp2, verbatim — best-total round; single-variable experiment.)

#define MBLK (N_NODES / 16)  // 625, exact

__global__ __launch_bounds__(512, 4) void k_mlp2(
    const float* __restrict__ hin, float* __restrict__ hc, float* __restrict__ uout,
    const float* __restrict__ W1, const float* __restrict__ b1,
    const float* __restrict__ g1, const float* __restrict__ be1,
    const float* __restrict__ W2, const float* __restrict__ b2,
    const float* __restrict__ lng, const float* __restrict__ lnb,
    int addRes, int writeU) {
  __shared__ float sW1[64 * 128];   // 32KB [k][j]
  __shared__ float sW2[128 * 64];   // 32KB [k][i]
  __shared__ float sH[8][128];      // per wave, h interleaved (k*2 + node)
  __shared__ float sZ[8][256];      // per wave, z interleaved (k*2 + node)

  int tid = threadIdx.x;
  int lane = tid & 63;
  int wv = tid >> 6;  // 0..7
  int gn0 = blockIdx.x * 16 + wv * 2;
  int gn1 = gn0 + 1;

  for (int i = tid; i < 2048; i += 512) ((float4*)sW1)[i] = ((const float4*)W1)[i];
  for (int i = tid; i < 2048; i += 512) ((float4*)sW2)[i] = ((const float4*)W2)[i];

  {
    float h0 = hin[gn0 * 64 + lane];
    float h1 = hin[gn1 * 64 + lane];
    *((float2*)&sH[wv][lane * 2]) = make_float2(h0, h1);
  }
  __syncthreads();

  int j0 = 2 * lane;
  float2 b1v = *((const float2*)&b1[j0]);
  float a00 = b1v.x, a01 = b1v.y, a10 = b1v.x, a11 = b1v.y;
#pragma unroll 8
  for (int k = 0; k < 64; k++) {
    float2 hp = *((float2*)&sH[wv][k * 2]);
    float2 wp = *((float2*)&sW1[k * 128 + j0]);
    a00 += hp.x * wp.x; a01 += hp.x * wp.y;
    a10 += hp.y * wp.x; a11 += hp.y * wp.y;
  }

  {
    float2 gv = *((const float2*)&g1[j0]);
    float2 bev = *((const float2*)&be1[j0]);
    float s0 = a00 + a01, q0 = a00 * a00 + a01 * a01;
    float s1 = a10 + a11, q1 = a10 * a10 + a11 * a11;
#pragma unroll
    for (int o = 32; o; o >>= 1) {
      s0 += __shfl_xor(s0, o); q0 += __shfl_xor(q0, o);
      s1 += __shfl_xor(s1, o); q1 += __shfl_xor(q1, o);
    }
    float mu0 = s0 * (1.f / 128.f), mu1 = s1 * (1.f / 128.f);
    float rs0 = rsqrtf(q0 * (1.f / 128.f) - mu0 * mu0 + 1e-5f);
    float rs1 = rsqrtf(q1 * (1.f / 128.f) - mu1 * mu1 + 1e-5f);
    float4 zv;
    zv.x = fmaxf((a00 - mu0) * rs0 * gv.x + bev.x, 0.f);
    zv.y = fmaxf((a10 - mu1) * rs1 * gv.x + bev.x, 0.f);
    zv.z = fmaxf((a01 - mu0) * rs0 * gv.y + bev.y, 0.f);
    zv.w = fmaxf((a11 - mu1) * rs1 * gv.y + bev.y, 0.f);
    *((float4*)&sZ[wv][4 * lane]) = zv;
  }

  float bo = b2[lane];
  float o0 = bo, o1 = bo;
#pragma unroll 8
  for (int k = 0; k < 128; k++) {
    float2 zp = *((float2*)&sZ[wv][k * 2]);
    float wv2 = sW2[k * 64 + lane];
    o0 += zp.x * wv2;
    o1 += zp.y * wv2;
  }

  float r0 = addRes ? hc[gn0 * 64 + lane] : 0.f;
  float r1 = addRes ? hc[gn1 * 64 + lane] : 0.f;
  float hcn0 = o0 + r0, hcn1 = o1 + r1;
  hc[gn0 * 64 + lane] = hcn0;
  hc[gn1 * 64 + lane] = hcn1;

  if (writeU) {
    float lg_ = lng[lane], lb_ = lnb[lane];
    float s0 = hcn0, q0 = hcn0 * hcn0;
    float s1 = hcn1, q1 = hcn1 * hcn1;
#pragma unroll
    for (int o = 32; o; o >>= 1) {
      s0 += __shfl_xor(s0, o); q0 += __shfl_xor(q0, o);
      s1 += __shfl_xor(s1, o); q1 += __shfl_xor(q1, o);
    }
    float mu0 = s0 * (1.f / 64.f), mu1 = s1 * (1.f / 64.f);
    float rs0 = rsqrtf(q0 * (1.f / 64.f) - mu0 * mu0 + 1e-5f);
    float rs1 = rsqrtf(q1 * (1.f / 64.f) - mu1 * mu1 + 1e-5f);
    uout[gn0 * 64 + lane] = fmaxf((hcn0 - mu0) * rs0 * lg_ + lb_, 0.f);
    uout[gn1 * 64 + lane] = fmaxf((hcn1 - mu1) * rs1 * lg_ + lb_, 0.f);
  }
}

// ---------------- final: out = relu(LN(hc, g0, b0)) @ W_out + b_out ----------------

__global__ __launch_bounds__(256) void k_final(const float* __restrict__ hc, const float* __restrict__ g,
                                               const float* __restrict__ bptr, const float* __restrict__ Wout,
                                               const float* __restrict__ bout, float* __restrict__ out) {
  __shared__ float sW[DIM * DIM];
  int tid = threadIdx.x;
  for (int i = tid; i < 1024; i += 256) ((float4*)sW)[i] = ((const float4*)Wout)[i];
  __syncthreads();
  int lane = tid & 63, w = tid >> 6;
  int n = blockIdx.x * 4 + w;
  if (n >= N_NODES) return;
  float v = hc[n * 64 + lane];
  float s = v, q = v * v;
#pragma unroll
  for (int o = 32; o; o >>= 1) { s += __shfl_xor(s, o); q += __shfl_xor(q, o); }
  float mu = s * (1.f / 64.f);
  float var = q * (1.f / 64.f) - mu * mu;
  float rs = rsqrtf(var + 1e-5f);
  float z = fmaxf((v - mu) * rs * g[lane] + bptr[lane], 0.f);
  float acc = bout[lane];
  for (int k = 0; k < 64; k++) {
    float zk = __shfl(z, k);
    acc += zk * sW[k * 64 + lane];
  }
  out[n * 64 + lane] = acc;
}

// ---------------- host ----------------

extern "C" void kernel_launch(void* const* d_in, const int* in_sizes, int n_in,
                              void* d_out, int out_size, void* d_ws, size_t ws_size,
                              hipStream_t stream) {
  const float* x        = (const float*)d_in[0];
  const float* eattr    = (const float*)d_in[1];
  const int*   src      = (const int*)d_in[2];
  const int*   dst      = (const int*)d_in[3];
  const float* W_node   = (const float*)d_in[4];
  const float* b_node   = (const float*)d_in[5];
  const float* W_edge   = (const float*)d_in[6];
  const float* b_edge   = (const float*)d_in[7];
  const float* t        = (const float*)d_in[8];
  const float* W1       = (const float*)d_in[9];
  const float* b1       = (const float*)d_in[10];
  const float* g1       = (const float*)d_in[11];
  const float* be1      = (const float*)d_in[12];
  const float* W2       = (const float*)d_in[13];
  const float* b2       = (const float*)d_in[14];
  const float* ln_g     = (const float*)d_in[15];
  const float* ln_b     = (const float*)d_in[16];
  const float* W_out    = (const float*)d_in[17];
  const float* b_out    = (const float*)d_in[18];
  float* out = (float*)d_out;

  char* w = (char*)d_ws;
  float* u       = (float*)w;  w += (size_t)N_NODES * 64 * 4;
  float* hcb     = (float*)w;  w += (size_t)N_NODES * 64 * 4;
  float* htmp    = (float*)w;  w += (size_t)N_NODES * 64 * 4;
  int* off       = (int*)w;    w += (size_t)(N_NODES + 1) * 4;
  int* cur       = (int*)w;    w += (size_t)N_NODES * 4;
  int* eids      = (int*)w;    w += (size_t)N_EDGES * 4;
  int* src_s     = (int*)w;    w += (size_t)N_EDGES * 4;
  float4* eattr_s = (float4*)w; w += (size_t)N_EDGES * 16;
  float* ea_s    = (float*)w;  w += (size_t)N_EDGES * 64 * 4;

  k_zero<<<(N_NODES + 255) / 256, 256, 0, stream>>>(cur, N_NODES);
  k_hist<<<(N_EDGES + 255) / 256, 256, 0, stream>>>(dst, cur);
  k_scan<<<1, 256, 0, stream>>>(cur, off);
  k_scatter<<<(N_EDGES + 255) / 256, 256, 0, stream>>>(dst, cur, eids);
  k_sortgather<<<(N_NODES + 3) / 4, 256, 0, stream>>>(off, eids, src, (const float4*)eattr,
                                                      src_s, eattr_s);
  k_ea<<<(N_EDGES * 64 + 255) / 256, 256, 0, stream>>>((const float4*)eattr_s, W_edge,
                                                       b_edge, ea_s);

  k_enc<<<(N_NODES * 64 + 255) / 256, 256, 0, stream>>>(x, W_node, b_node, hcb, u);

  for (int l = 0; l < LAYERS; l++) {
    k_edge<<<(N_NODES + 3) / 4, 256, 0, stream>>>(u, ea_s, src_s, off, t, l, htmp);
    int nxt = (l + 1 < LAYERS) ? (l + 1) : 0;  // unused when writeU=0
    k_mlp2<<<MBLK, 512, 0, stream>>>(htmp, hcb, u,
                                     W1 + (size_t)l * DIM * HID, b1 + (size_t)l * HID,
                                     g1 + (size_t)l * HID, be1 + (size_t)l * HID,
                                     W2 + (size_t)l * HID * DIM, b2 + (size_t)l * DIM,
                                     ln_g + (size_t)nxt * DIM, ln_b + (size_t)nxt * DIM,
                                     (l > 0) ? 1 : 0, (l < LAYERS - 1) ? 1 : 0);
  }

  k_final<<<(N_NODES + 3) / 4, 256, 0, stream>>>(hcb, ln_g, ln_b, W_out, b_out, out);
}

// Round 9
// 988.921 us; speedup vs baseline: 1.7303x; 1.0156x over previous
//
#include <hip/hip_runtime.h>

#define N_NODES 10000
#define N_EDGES 160000
#define NUM_FEAT 14
#define EDGE_DIM 4
#define DIM 64
#define HID 128
#define LAYERS 28

#define NEG_INF (-__builtin_inff())

// async global->LDS, 16B/lane: gsrc per-lane (base + lane*4 floats), lds_base
// wave-uniform; HW writes lds_base + lane*16.
__device__ __forceinline__ void stage16(const float* gsrc, float* lds_base) {
  __builtin_amdgcn_global_load_lds(
      (const __attribute__((address_space(1))) void*)gsrc,
      (__attribute__((address_space(3))) void*)lds_base, 16, 0, 0);
}

// ---------------- CSR build ----------------

__global__ __launch_bounds__(256) void k_hist(const int* __restrict__ dst, int* __restrict__ cur) {
  int e = blockIdx.x * 256 + threadIdx.x;
  if (e < N_EDGES) atomicAdd(&cur[dst[e]], 1);
}

__global__ __launch_bounds__(256) void k_scan(int* __restrict__ cur, int* __restrict__ off) {
  __shared__ int part[256];
  int t = threadIdx.x;
  const int CH = 40;
  int base = t * CH;
  int s = 0;
  for (int i = 0; i < CH; i++) {
    int idx = base + i;
    if (idx < N_NODES) s += cur[idx];
  }
  part[t] = s;
  __syncthreads();
  for (int ofs = 1; ofs < 256; ofs <<= 1) {
    int tmp = (t >= ofs) ? part[t - ofs] : 0;
    __syncthreads();
    part[t] += tmp;
    __syncthreads();
  }
  int run = part[t] - s;
  for (int i = 0; i < CH; i++) {
    int idx = base + i;
    if (idx < N_NODES) {
      int d = cur[idx];
      off[idx] = run;
      cur[idx] = run;
      run += d;
    }
  }
  if (t == 255) off[N_NODES] = part[255];
}

__global__ __launch_bounds__(256) void k_scatter(const int* __restrict__ dst, int* __restrict__ cur,
                                                 int* __restrict__ eids) {
  int e = blockIdx.x * 256 + threadIdx.x;
  if (e < N_EDGES) {
    int p = atomicAdd(&cur[dst[e]], 1);
    eids[p] = e;
  }
}

// wave-per-node bitonic sort by edge id, then gather src and write the
// precomputed edge embedding ea_s[slot][f] = b_edge[f] + eattr[e]@W_edge[:,f]
// directly (shfl-broadcast of the sorted eattr within the wave).
__global__ __launch_bounds__(256) void k_sortgather(
    const int* __restrict__ off, const int* __restrict__ eids,
    const int* __restrict__ src, const float4* __restrict__ eattr,
    const float* __restrict__ W_edge, const float* __restrict__ b_edge,
    int* __restrict__ src_s, float4* __restrict__ eattr_s, float* __restrict__ ea_s) {
  int node = blockIdx.x * 4 + (threadIdx.x >> 6);
  int lane = threadIdx.x & 63;
  if (node >= N_NODES) return;
  float we0 = W_edge[lane], we1 = W_edge[64 + lane], we2 = W_edge[128 + lane],
        we3 = W_edge[192 + lane];
  float be = b_edge[lane];
  int a = off[node];
  int d = off[node + 1] - a;
  if (d <= 64) {
    int key = (lane < d) ? eids[a + lane] : 0x7fffffff;
#pragma unroll
    for (int k = 2; k <= 64; k <<= 1) {
      for (int j = k >> 1; j > 0; j >>= 1) {
        int p = __shfl_xor(key, j);
        bool dirUp = ((lane & k) == 0);
        bool isLower = ((lane & j) == 0);
        key = ((isLower == dirUp) ? min(key, p) : max(key, p));
      }
    }
    float4 ev = make_float4(0.f, 0.f, 0.f, 0.f);
    if (lane < d) {
      src_s[a + lane] = src[key];
      ev = eattr[key];
    }
    for (int j = 0; j < d; j++) {
      float ex = __shfl(ev.x, j), ey = __shfl(ev.y, j),
            ez = __shfl(ev.z, j), ew = __shfl(ev.w, j);
      ea_s[(size_t)(a + j) * 64 + lane] =
          be + ex * we0 + ey * we1 + ez * we2 + ew * we3;
    }
  } else {
    // rare fallback (degree > 64): counting rank, then serial ea pass
    for (int i = lane; i < d; i += 64) {
      int e = eids[a + i];
      int r = 0;
      for (int j = 0; j < d; j++) r += (eids[a + j] < e) ? 1 : 0;
      src_s[a + r] = src[e];
      eattr_s[a + r] = eattr[e];
    }
    for (int j = 0; j < d; j++) {
      float4 e4 = eattr_s[a + j];
      ea_s[(size_t)(a + j) * 64 + lane] =
          be + e4.x * we0 + e4.y * we1 + e4.z * we2 + e4.w * we3;
    }
  }
}

// ---------------- node encoder ----------------

__global__ __launch_bounds__(256) void k_enc(const float* __restrict__ x, const float* __restrict__ Wn,
                                             const float* __restrict__ bn, float* __restrict__ hc,
                                             float* __restrict__ u) {
  int gid = blockIdx.x * 256 + threadIdx.x;
  if (gid >= N_NODES * DIM) return;
  int n = gid >> 6, j = gid & 63;
  float acc = bn[j];
#pragma unroll
  for (int k = 0; k < NUM_FEAT; k++) acc += x[n * NUM_FEAT + k] * Wn[k * DIM + j];
  hc[gid] = acc;
  u[gid] = acc;
}

// ---------------- edge aggregation: 1 node/wave, max-free softmax ----------------
// t=1 and u=relu(LN(.)) bounded => logits <= ~6, exp cannot overflow; the
// reference's segment_max subtraction cancels exactly in e/s. Per edge:
// 1 s_load (src), 2 coalesced 256B loads (u row, ea row), ~7 VALU on two
// independent accumulator chains. Fixed slot order => deterministic.

__global__ __launch_bounds__(256) void k_edge(
    const float* __restrict__ uin, const float* __restrict__ ea_s,
    const int* __restrict__ src_s, const int* __restrict__ off,
    const float* __restrict__ tptr, int layer, float* __restrict__ htmp) {
  int node = __builtin_amdgcn_readfirstlane((blockIdx.x << 2) + (threadIdx.x >> 6));
  int lane = threadIdx.x & 63;
  float tv = tptr[layer];
  int a = off[node], d = off[node + 1] - a;  // scalar
  float un = uin[(node << 6) + lane];
  float s0 = 0.f, s1 = 0.f, ac0 = 0.f, ac1 = 0.f;
  int i = 0;
  for (; i + 8 <= d; i += 8) {
    float uv[8], ev[8];
#pragma unroll
    for (int j = 0; j < 8; j++) {
      int sn = src_s[a + i + j];                      // s_load
      uv[j] = uin[(sn << 6) + lane];                  // sgpr-base gather
      ev[j] = ea_s[(size_t)(a + i + j) * 64 + lane];  // coalesced stream
    }
#pragma unroll
    for (int j = 0; j < 8; j++) {
      float msg = fmaxf(uv[j] + ev[j], 0.f) + 1e-7f;
      float e = __expf(msg * tv);
      if (j & 1) {
        s1 += e;
        ac1 = fmaf(e, msg, ac1);
      } else {
        s0 += e;
        ac0 = fmaf(e, msg, ac0);
      }
    }
  }
  for (; i < d; i++) {
    int sn = src_s[a + i];
    float msg = fmaxf(uin[(sn << 6) + lane] + ea_s[(size_t)(a + i) * 64 + lane], 0.f) + 1e-7f;
    float e = __expf(msg * tv);
    s0 += e;
    ac0 = fmaf(e, msg, ac0);
  }
  float sum = s0 + s1, acc = ac0 + ac1;
  htmp[(node << 6) + lane] = acc / (sum + 1e-16f) + un;
}

// ---------------- MLP: 512 threads (8 waves), 2 nodes/wave, 16 nodes/block ----------------
// R5 structure; weights staged via global_load_lds (no VGPR round-trip).

#define MBLK (N_NODES / 16)  // 625, exact

__global__ __launch_bounds__(512, 4) void k_mlp2(
    const float* __restrict__ hin, float* __restrict__ hc, float* __restrict__ uout,
    const float* __restrict__ W1, const float* __restrict__ b1,
    const float* __restrict__ g1, const float* __restrict__ be1,
    const float* __restrict__ W2, const float* __restrict__ b2,
    const float* __restrict__ lng, const float* __restrict__ lnb,
    int addRes, int writeU) {
  __shared__ float sW1[64 * 128];   // 32KB [k][j]
  __shared__ float sW2[128 * 64];   // 32KB [k][i]
  __shared__ float sH[8][128];      // per wave, h interleaved (k*2 + node)
  __shared__ float sZ[8][256];      // per wave, z interleaved (k*2 + node)

  int tid = threadIdx.x;
  int lane = tid & 63;
  int wv = tid >> 6;  // 0..7
  int gn0 = blockIdx.x * 16 + wv * 2;
  int gn1 = gn0 + 1;

  // async weight staging: wave wv owns floats [wv*1024, wv*1024+1024)
  {
    const float* w1s = W1 + wv * 1024;
    const float* w2s = W2 + wv * 1024;
    float* d1 = sW1 + wv * 1024;
    float* d2 = sW2 + wv * 1024;
#pragma unroll
    for (int r = 0; r < 4; r++) {
      stage16(w1s + r * 256 + lane * 4, d1 + r * 256);
      stage16(w2s + r * 256 + lane * 4, d2 + r * 256);
    }
  }

  {
    float h0 = hin[gn0 * 64 + lane];
    float h1 = hin[gn1 * 64 + lane];
    *((float2*)&sH[wv][lane * 2]) = make_float2(h0, h1);
  }
  __syncthreads();  // drains global_load_lds (vmcnt) + sH

  int j0 = 2 * lane;
  float2 b1v = *((const float2*)&b1[j0]);
  float a00 = b1v.x, a01 = b1v.y, a10 = b1v.x, a11 = b1v.y;
#pragma unroll 8
  for (int k = 0; k < 64; k++) {
    float2 hp = *((float2*)&sH[wv][k * 2]);
    float2 wp = *((float2*)&sW1[k * 128 + j0]);
    a00 += hp.x * wp.x; a01 += hp.x * wp.y;
    a10 += hp.y * wp.x; a11 += hp.y * wp.y;
  }

  {
    float2 gv = *((const float2*)&g1[j0]);
    float2 bev = *((const float2*)&be1[j0]);
    float s0 = a00 + a01, q0 = a00 * a00 + a01 * a01;
    float s1 = a10 + a11, q1 = a10 * a10 + a11 * a11;
#pragma unroll
    for (int o = 32; o; o >>= 1) {
      s0 += __shfl_xor(s0, o); q0 += __shfl_xor(q0, o);
      s1 += __shfl_xor(s1, o); q1 += __shfl_xor(q1, o);
    }
    float mu0 = s0 * (1.f / 128.f), mu1 = s1 * (1.f / 128.f);
    float rs0 = rsqrtf(q0 * (1.f / 128.f) - mu0 * mu0 + 1e-5f);
    float rs1 = rsqrtf(q1 * (1.f / 128.f) - mu1 * mu1 + 1e-5f);
    float4 zv;
    zv.x = fmaxf((a00 - mu0) * rs0 * gv.x + bev.x, 0.f);
    zv.y = fmaxf((a10 - mu1) * rs1 * gv.x + bev.x, 0.f);
    zv.z = fmaxf((a01 - mu0) * rs0 * gv.y + bev.y, 0.f);
    zv.w = fmaxf((a11 - mu1) * rs1 * gv.y + bev.y, 0.f);
    *((float4*)&sZ[wv][4 * lane]) = zv;
  }

  float bo = b2[lane];
  float o0 = bo, o1 = bo;
#pragma unroll 8
  for (int k = 0; k < 128; k++) {
    float2 zp = *((float2*)&sZ[wv][k * 2]);
    float wv2 = sW2[k * 64 + lane];
    o0 += zp.x * wv2;
    o1 += zp.y * wv2;
  }

  float r0 = addRes ? hc[gn0 * 64 + lane] : 0.f;
  float r1 = addRes ? hc[gn1 * 64 + lane] : 0.f;
  float hcn0 = o0 + r0, hcn1 = o1 + r1;
  hc[gn0 * 64 + lane] = hcn0;
  hc[gn1 * 64 + lane] = hcn1;

  if (writeU) {
    float lg_ = lng[lane], lb_ = lnb[lane];
    float s0 = hcn0, q0 = hcn0 * hcn0;
    float s1 = hcn1, q1 = hcn1 * hcn1;
#pragma unroll
    for (int o = 32; o; o >>= 1) {
      s0 += __shfl_xor(s0, o); q0 += __shfl_xor(q0, o);
      s1 += __shfl_xor(s1, o); q1 += __shfl_xor(q1, o);
    }
    float mu0 = s0 * (1.f / 64.f), mu1 = s1 * (1.f / 64.f);
    float rs0 = rsqrtf(q0 * (1.f / 64.f) - mu0 * mu0 + 1e-5f);
    float rs1 = rsqrtf(q1 * (1.f / 64.f) - mu1 * mu1 + 1e-5f);
    uout[gn0 * 64 + lane] = fmaxf((hcn0 - mu0) * rs0 * lg_ + lb_, 0.f);
    uout[gn1 * 64 + lane] = fmaxf((hcn1 - mu1) * rs1 * lg_ + lb_, 0.f);
  }
}

// ---------------- final: out = relu(LN(hc, g0, b0)) @ W_out + b_out ----------------

__global__ __launch_bounds__(256) void k_final(const float* __restrict__ hc, const float* __restrict__ g,
                                               const float* __restrict__ bptr, const float* __restrict__ Wout,
                                               const float* __restrict__ bout, float* __restrict__ out) {
  __shared__ float sW[DIM * DIM];
  int tid = threadIdx.x;
  for (int i = tid; i < 1024; i += 256) ((float4*)sW)[i] = ((const float4*)Wout)[i];
  __syncthreads();
  int lane = tid & 63, w = tid >> 6;
  int n = blockIdx.x * 4 + w;
  if (n >= N_NODES) return;
  float v = hc[n * 64 + lane];
  float s = v, q = v * v;
#pragma unroll
  for (int o = 32; o; o >>= 1) { s += __shfl_xor(s, o); q += __shfl_xor(q, o); }
  float mu = s * (1.f / 64.f);
  float var = q * (1.f / 64.f) - mu * mu;
  float rs = rsqrtf(var + 1e-5f);
  float z = fmaxf((v - mu) * rs * g[lane] + bptr[lane], 0.f);
  float acc = bout[lane];
  for (int k = 0; k < 64; k++) {
    float zk = __shfl(z, k);
    acc += zk * sW[k * 64 + lane];
  }
  out[n * 64 + lane] = acc;
}

// ---------------- host ----------------

extern "C" void kernel_launch(void* const* d_in, const int* in_sizes, int n_in,
                              void* d_out, int out_size, void* d_ws, size_t ws_size,
                              hipStream_t stream) {
  const float* x        = (const float*)d_in[0];
  const float* eattr    = (const float*)d_in[1];
  const int*   src      = (const int*)d_in[2];
  const int*   dst      = (const int*)d_in[3];
  const float* W_node   = (const float*)d_in[4];
  const float* b_node   = (const float*)d_in[5];
  const float* W_edge   = (const float*)d_in[6];
  const float* b_edge   = (const float*)d_in[7];
  const float* t        = (const float*)d_in[8];
  const float* W1       = (const float*)d_in[9];
  const float* b1       = (const float*)d_in[10];
  const float* g1       = (const float*)d_in[11];
  const float* be1      = (const float*)d_in[12];
  const float* W2       = (const float*)d_in[13];
  const float* b2       = (const float*)d_in[14];
  const float* ln_g     = (const float*)d_in[15];
  const float* ln_b     = (const float*)d_in[16];
  const float* W_out    = (const float*)d_in[17];
  const float* b_out    = (const float*)d_in[18];
  float* out = (float*)d_out;

  char* w = (char*)d_ws;
  float* u       = (float*)w;  w += (size_t)N_NODES * 64 * 4;
  float* hcb     = (float*)w;  w += (size_t)N_NODES * 64 * 4;
  float* htmp    = (float*)w;  w += (size_t)N_NODES * 64 * 4;
  int* off       = (int*)w;    w += (size_t)(N_NODES + 1) * 4;
  int* cur       = (int*)w;    w += (size_t)N_NODES * 4;
  int* eids      = (int*)w;    w += (size_t)N_EDGES * 4;
  int* src_s     = (int*)w;    w += (size_t)N_EDGES * 4;
  float4* eattr_s = (float4*)w; w += (size_t)N_EDGES * 16;
  float* ea_s    = (float*)w;  w += (size_t)N_EDGES * 64 * 4;

  hipMemsetAsync(cur, 0, (size_t)N_NODES * 4, stream);
  k_hist<<<(N_EDGES + 255) / 256, 256, 0, stream>>>(dst, cur);
  k_scan<<<1, 256, 0, stream>>>(cur, off);
  k_scatter<<<(N_EDGES + 255) / 256, 256, 0, stream>>>(dst, cur, eids);
  k_sortgather<<<(N_NODES + 3) / 4, 256, 0, stream>>>(off, eids, src, (const float4*)eattr,
                                                      W_edge, b_edge, src_s, eattr_s, ea_s);

  k_enc<<<(N_NODES * 64 + 255) / 256, 256, 0, stream>>>(x, W_node, b_node, hcb, u);

  for (int l = 0; l < LAYERS; l++) {
    k_edge<<<(N_NODES + 3) / 4, 256, 0, stream>>>(u, ea_s, src_s, off, t, l, htmp);
    int nxt = (l + 1 < LAYERS) ? (l + 1) : 0;  // unused when writeU=0
    k_mlp2<<<MBLK, 512, 0, stream>>>(htmp, hcb, u,
                                     W1 + (size_t)l * DIM * HID, b1 + (size_t)l * HID,
                                     g1 + (size_t)l * HID, be1 + (size_t)l * HID,
                                     W2 + (size_t)l * HID * DIM, b2 + (size_t)l * DIM,
                                     ln_g + (size_t)nxt * DIM, ln_b + (size_t)nxt * DIM,
                                     (l > 0) ? 1 : 0, (l < LAYERS - 1) ? 1 : 0);
  }

  k_final<<<(N_NODES + 3) / 4, 256, 0, stream>>>(hcb, ln_g, ln_b, W_out, b_out, out);
}

// Round 10
// 925.382 us; speedup vs baseline: 1.8491x; 1.0687x over previous
//
#include <hip/hip_runtime.h>

#define N_NODES 10000
#define N_EDGES 160000
#define NUM_FEAT 14
#define EDGE_DIM 4
#define DIM 64
#define HID 128
#define LAYERS 28

// async global->LDS, 16B/lane: gsrc per-lane (base + lane*4 floats), lds_base
// wave-uniform; HW writes lds_base + lane*16.
__device__ __forceinline__ void stage16(const float* gsrc, float* lds_base) {
  __builtin_amdgcn_global_load_lds(
      (const __attribute__((address_space(1))) void*)gsrc,
      (__attribute__((address_space(3))) void*)lds_base, 16, 0, 0);
}

// ---------------- CSR build ----------------

__global__ __launch_bounds__(256) void k_hist(const int* __restrict__ dst, int* __restrict__ cur) {
  int e = blockIdx.x * 256 + threadIdx.x;
  if (e < N_EDGES) atomicAdd(&cur[dst[e]], 1);
}

__global__ __launch_bounds__(256) void k_scan(int* __restrict__ cur, int* __restrict__ off) {
  __shared__ int part[256];
  int t = threadIdx.x;
  const int CH = 40;
  int base = t * CH;
  int s = 0;
  for (int i = 0; i < CH; i++) {
    int idx = base + i;
    if (idx < N_NODES) s += cur[idx];
  }
  part[t] = s;
  __syncthreads();
  for (int ofs = 1; ofs < 256; ofs <<= 1) {
    int tmp = (t >= ofs) ? part[t - ofs] : 0;
    __syncthreads();
    part[t] += tmp;
    __syncthreads();
  }
  int run = part[t] - s;
  for (int i = 0; i < CH; i++) {
    int idx = base + i;
    if (idx < N_NODES) {
      int d = cur[idx];
      off[idx] = run;
      cur[idx] = run;
      run += d;
    }
  }
  if (t == 255) off[N_NODES] = part[255];
}

__global__ __launch_bounds__(256) void k_scatter(const int* __restrict__ dst, int* __restrict__ cur,
                                                 int* __restrict__ eids) {
  int e = blockIdx.x * 256 + threadIdx.x;
  if (e < N_EDGES) {
    int p = atomicAdd(&cur[dst[e]], 1);
    eids[p] = e;
  }
}

// wave-per-node bitonic sort by edge id, then gather src and write the
// precomputed edge embedding ea_s[slot][f] = b_edge[f] + eattr[e]@W_edge[:,f].
__global__ __launch_bounds__(256) void k_sortgather(
    const int* __restrict__ off, const int* __restrict__ eids,
    const int* __restrict__ src, const float4* __restrict__ eattr,
    const float* __restrict__ W_edge, const float* __restrict__ b_edge,
    int* __restrict__ src_s, float4* __restrict__ eattr_s, float* __restrict__ ea_s) {
  int node = blockIdx.x * 4 + (threadIdx.x >> 6);
  int lane = threadIdx.x & 63;
  if (node >= N_NODES) return;
  float we0 = W_edge[lane], we1 = W_edge[64 + lane], we2 = W_edge[128 + lane],
        we3 = W_edge[192 + lane];
  float be = b_edge[lane];
  int a = off[node];
  int d = off[node + 1] - a;
  if (d <= 64) {
    int key = (lane < d) ? eids[a + lane] : 0x7fffffff;
#pragma unroll
    for (int k = 2; k <= 64; k <<= 1) {
      for (int j = k >> 1; j > 0; j >>= 1) {
        int p = __shfl_xor(key, j);
        bool dirUp = ((lane & k) == 0);
        bool isLower = ((lane & j) == 0);
        key = ((isLower == dirUp) ? min(key, p) : max(key, p));
      }
    }
    float4 ev = make_float4(0.f, 0.f, 0.f, 0.f);
    if (lane < d) {
      src_s[a + lane] = src[key];
      ev = eattr[key];
    }
    for (int j = 0; j < d; j++) {
      float ex = __shfl(ev.x, j), ey = __shfl(ev.y, j),
            ez = __shfl(ev.z, j), ew = __shfl(ev.w, j);
      ea_s[(size_t)(a + j) * 64 + lane] =
          be + ex * we0 + ey * we1 + ez * we2 + ew * we3;
    }
  } else {
    for (int i = lane; i < d; i += 64) {
      int e = eids[a + i];
      int r = 0;
      for (int j = 0; j < d; j++) r += (eids[a + j] < e) ? 1 : 0;
      src_s[a + r] = src[e];
      eattr_s[a + r] = eattr[e];
    }
    for (int j = 0; j < d; j++) {
      float4 e4 = eattr_s[a + j];
      ea_s[(size_t)(a + j) * 64 + lane] =
          be + e4.x * we0 + e4.y * we1 + e4.z * we2 + e4.w * we3;
    }
  }
}

// ---------------- node encoder ----------------

__global__ __launch_bounds__(256) void k_enc(const float* __restrict__ x, const float* __restrict__ Wn,
                                             const float* __restrict__ bn, float* __restrict__ hc,
                                             float* __restrict__ u) {
  int gid = blockIdx.x * 256 + threadIdx.x;
  if (gid >= N_NODES * DIM) return;
  int n = gid >> 6, j = gid & 63;
  float acc = bn[j];
#pragma unroll
  for (int k = 0; k < NUM_FEAT; k++) acc += x[n * NUM_FEAT + k] * Wn[k * DIM + j];
  hc[gid] = acc;
  u[gid] = acc;
}

// ---------------- fused layer: edge-agg + MLP, one dispatch, one barrier ----------------
// 640 threads (10 waves), 20 nodes/block, 500 blocks (exact; ~0.98 of 2-block/CU
// capacity -> no quantization tail). Wave wv owns nodes wv*2, wv*2+1 end-to-end:
//   stage W1/W2 via global_load_lds (issue-early, fire-and-forget)
//   edge agg per node (scalar metadata, max-free softmax, batch-8) -> sH[wv]
//   __syncthreads (drains staging; sH/sZ are wave-private)
//   GEMM1 -> LN(shfl) -> sZ[wv] -> GEMM2 -> residual -> pre-LN -> uout

#define NPB 20
#define NLB (N_NODES / NPB)  // 500

__global__ __launch_bounds__(640, 5) void k_layer(
    const float* __restrict__ uin, float* __restrict__ hc, float* __restrict__ uout,
    const float* __restrict__ ea_s, const int* __restrict__ src_s,
    const int* __restrict__ off, const float* __restrict__ tptr, int layer,
    const float* __restrict__ W1, const float* __restrict__ b1,
    const float* __restrict__ g1, const float* __restrict__ be1,
    const float* __restrict__ W2, const float* __restrict__ b2,
    const float* __restrict__ lng, const float* __restrict__ lnb,
    int addRes, int writeU) {
  __shared__ float sW1[64 * 128];   // 32KB [k][j]
  __shared__ float sW2[128 * 64];   // 32KB [k][i]
  __shared__ float sH[10][128];     // 5KB  per wave, h interleaved (k*2 + node)
  __shared__ float sZ[10][256];     // 10KB per wave, z interleaved (k*2 + node)

  const int tid = threadIdx.x;
  const int lane = tid & 63;
  const int wv = tid >> 6;  // 0..9
  const int nbase = blockIdx.x * NPB;

  // ---- issue weight staging (fire-and-forget; drained by the barrier) ----
  for (int c = wv; c < 32; c += 10) {
    stage16(W1 + c * 256 + lane * 4, sW1 + c * 256);
    stage16(W2 + c * 256 + lane * 4, sW2 + c * 256);
  }

  // ---- edge aggregation: 2 nodes per wave, max-free softmax ----
  {
    float tv = tptr[layer];
    float hpair[2];
#pragma unroll
    for (int q = 0; q < 2; q++) {
      int gn = __builtin_amdgcn_readfirstlane(nbase + wv * 2 + q);
      int a = off[gn], d = off[gn + 1] - a;  // scalar
      float un = uin[(gn << 6) + lane];
      float s0 = 0.f, s1 = 0.f, ac0 = 0.f, ac1 = 0.f;
      int i = 0;
      for (; i + 8 <= d; i += 8) {
        float uv[8], ev[8];
#pragma unroll
        for (int j = 0; j < 8; j++) {
          int sn = src_s[a + i + j];                      // s_load
          uv[j] = uin[(sn << 6) + lane];                  // sgpr-base gather
          ev[j] = ea_s[(size_t)(a + i + j) * 64 + lane];  // coalesced stream
        }
#pragma unroll
        for (int j = 0; j < 8; j++) {
          float msg = fmaxf(uv[j] + ev[j], 0.f) + 1e-7f;
          float e = __expf(msg * tv);
          if (j & 1) {
            s1 += e;
            ac1 = fmaf(e, msg, ac1);
          } else {
            s0 += e;
            ac0 = fmaf(e, msg, ac0);
          }
        }
      }
      for (; i < d; i++) {
        int sn = src_s[a + i];
        float msg = fmaxf(uin[(sn << 6) + lane] + ea_s[(size_t)(a + i) * 64 + lane],
                          0.f) + 1e-7f;
        float e = __expf(msg * tv);
        s0 += e;
        ac0 = fmaf(e, msg, ac0);
      }
      hpair[q] = (ac0 + ac1) / (s0 + s1 + 1e-16f) + un;
    }
    *((float2*)&sH[wv][lane * 2]) = make_float2(hpair[0], hpair[1]);
  }
  __syncthreads();  // drains global_load_lds; sH is wave-private anyway

  const int gn0 = nbase + wv * 2;
  const int gn1 = gn0 + 1;

  // ---- GEMM1: cols j0=2*lane, j0+1; 2 nodes ----
  int j0 = 2 * lane;
  float2 b1v = *((const float2*)&b1[j0]);
  float a00 = b1v.x, a01 = b1v.y, a10 = b1v.x, a11 = b1v.y;
#pragma unroll 8
  for (int k = 0; k < 64; k++) {
    float2 hp = *((float2*)&sH[wv][k * 2]);
    float2 wp = *((float2*)&sW1[k * 128 + j0]);
    a00 += hp.x * wp.x; a01 += hp.x * wp.y;
    a10 += hp.y * wp.x; a11 += hp.y * wp.y;
  }

  // ---- LN1 (over 128) via shfl; z -> LDS interleaved ----
  {
    float2 gv = *((const float2*)&g1[j0]);
    float2 bev = *((const float2*)&be1[j0]);
    float s0 = a00 + a01, q0 = a00 * a00 + a01 * a01;
    float s1 = a10 + a11, q1 = a10 * a10 + a11 * a11;
#pragma unroll
    for (int o = 32; o; o >>= 1) {
      s0 += __shfl_xor(s0, o); q0 += __shfl_xor(q0, o);
      s1 += __shfl_xor(s1, o); q1 += __shfl_xor(q1, o);
    }
    float mu0 = s0 * (1.f / 128.f), mu1 = s1 * (1.f / 128.f);
    float rs0 = rsqrtf(q0 * (1.f / 128.f) - mu0 * mu0 + 1e-5f);
    float rs1 = rsqrtf(q1 * (1.f / 128.f) - mu1 * mu1 + 1e-5f);
    float4 zv;
    zv.x = fmaxf((a00 - mu0) * rs0 * gv.x + bev.x, 0.f);
    zv.y = fmaxf((a10 - mu1) * rs1 * gv.x + bev.x, 0.f);
    zv.z = fmaxf((a01 - mu0) * rs0 * gv.y + bev.y, 0.f);
    zv.w = fmaxf((a11 - mu1) * rs1 * gv.y + bev.y, 0.f);
    *((float4*)&sZ[wv][4 * lane]) = zv;
  }

  // ---- GEMM2: col i=lane; 2 nodes ----
  float bo = b2[lane];
  float o0 = bo, o1 = bo;
#pragma unroll 8
  for (int k = 0; k < 128; k++) {
    float2 zp = *((float2*)&sZ[wv][k * 2]);
    float wv2 = sW2[k * 64 + lane];
    o0 += zp.x * wv2;
    o1 += zp.y * wv2;
  }

  // ---- residual + hc write ----
  float r0 = addRes ? hc[gn0 * 64 + lane] : 0.f;
  float r1 = addRes ? hc[gn1 * 64 + lane] : 0.f;
  float hcn0 = o0 + r0, hcn1 = o1 + r1;
  hc[gn0 * 64 + lane] = hcn0;
  hc[gn1 * 64 + lane] = hcn1;

  // ---- next-layer pre-LN: uout = relu(LN(hc)) ----
  if (writeU) {
    float lg_ = lng[lane], lb_ = lnb[lane];
    float s0 = hcn0, q0 = hcn0 * hcn0;
    float s1 = hcn1, q1 = hcn1 * hcn1;
#pragma unroll
    for (int o = 32; o; o >>= 1) {
      s0 += __shfl_xor(s0, o); q0 += __shfl_xor(q0, o);
      s1 += __shfl_xor(s1, o); q1 += __shfl_xor(q1, o);
    }
    float mu0 = s0 * (1.f / 64.f), mu1 = s1 * (1.f / 64.f);
    float rs0 = rsqrtf(q0 * (1.f / 64.f) - mu0 * mu0 + 1e-5f);
    float rs1 = rsqrtf(q1 * (1.f / 64.f) - mu1 * mu1 + 1e-5f);
    uout[gn0 * 64 + lane] = fmaxf((hcn0 - mu0) * rs0 * lg_ + lb_, 0.f);
    uout[gn1 * 64 + lane] = fmaxf((hcn1 - mu1) * rs1 * lg_ + lb_, 0.f);
  }
}

// ---------------- final: out = relu(LN(hc, g0, b0)) @ W_out + b_out ----------------

__global__ __launch_bounds__(256) void k_final(const float* __restrict__ hc, const float* __restrict__ g,
                                               const float* __restrict__ bptr, const float* __restrict__ Wout,
                                               const float* __restrict__ bout, float* __restrict__ out) {
  __shared__ float sW[DIM * DIM];
  int tid = threadIdx.x;
  for (int i = tid; i < 1024; i += 256) ((float4*)sW)[i] = ((const float4*)Wout)[i];
  __syncthreads();
  int lane = tid & 63, w = tid >> 6;
  int n = blockIdx.x * 4 + w;
  if (n >= N_NODES) return;
  float v = hc[n * 64 + lane];
  float s = v, q = v * v;
#pragma unroll
  for (int o = 32; o; o >>= 1) { s += __shfl_xor(s, o); q += __shfl_xor(q, o); }
  float mu = s * (1.f / 64.f);
  float var = q * (1.f / 64.f) - mu * mu;
  float rs = rsqrtf(var + 1e-5f);
  float z = fmaxf((v - mu) * rs * g[lane] + bptr[lane], 0.f);
  float acc = bout[lane];
  for (int k = 0; k < 64; k++) {
    float zk = __shfl(z, k);
    acc += zk * sW[k * 64 + lane];
  }
  out[n * 64 + lane] = acc;
}

// ---------------- host ----------------

extern "C" void kernel_launch(void* const* d_in, const int* in_sizes, int n_in,
                              void* d_out, int out_size, void* d_ws, size_t ws_size,
                              hipStream_t stream) {
  const float* x        = (const float*)d_in[0];
  const float* eattr    = (const float*)d_in[1];
  const int*   src      = (const int*)d_in[2];
  const int*   dst      = (const int*)d_in[3];
  const float* W_node   = (const float*)d_in[4];
  const float* b_node   = (const float*)d_in[5];
  const float* W_edge   = (const float*)d_in[6];
  const float* b_edge   = (const float*)d_in[7];
  const float* t        = (const float*)d_in[8];
  const float* W1       = (const float*)d_in[9];
  const float* b1       = (const float*)d_in[10];
  const float* g1       = (const float*)d_in[11];
  const float* be1      = (const float*)d_in[12];
  const float* W2       = (const float*)d_in[13];
  const float* b2       = (const float*)d_in[14];
  const float* ln_g     = (const float*)d_in[15];
  const float* ln_b     = (const float*)d_in[16];
  const float* W_out    = (const float*)d_in[17];
  const float* b_out    = (const float*)d_in[18];
  float* out = (float*)d_out;

  char* w = (char*)d_ws;
  float* uA      = (float*)w;  w += (size_t)N_NODES * 64 * 4;
  float* uB      = (float*)w;  w += (size_t)N_NODES * 64 * 4;
  float* hcb     = (float*)w;  w += (size_t)N_NODES * 64 * 4;
  int* off       = (int*)w;    w += (size_t)(N_NODES + 1) * 4;
  int* cur       = (int*)w;    w += (size_t)N_NODES * 4;
  int* eids      = (int*)w;    w += (size_t)N_EDGES * 4;
  int* src_s     = (int*)w;    w += (size_t)N_EDGES * 4;
  float4* eattr_s = (float4*)w; w += (size_t)N_EDGES * 16;
  float* ea_s    = (float*)w;  w += (size_t)N_EDGES * 64 * 4;

  hipMemsetAsync(cur, 0, (size_t)N_NODES * 4, stream);
  k_hist<<<(N_EDGES + 255) / 256, 256, 0, stream>>>(dst, cur);
  k_scan<<<1, 256, 0, stream>>>(cur, off);
  k_scatter<<<(N_EDGES + 255) / 256, 256, 0, stream>>>(dst, cur, eids);
  k_sortgather<<<(N_NODES + 3) / 4, 256, 0, stream>>>(off, eids, src, (const float4*)eattr,
                                                      W_edge, b_edge, src_s, eattr_s, ea_s);

  k_enc<<<(N_NODES * 64 + 255) / 256, 256, 0, stream>>>(x, W_node, b_node, hcb, uA);

  for (int l = 0; l < LAYERS; l++) {
    const float* uin = (l & 1) ? uB : uA;
    float* uo        = (l & 1) ? uA : uB;
    int nxt = (l + 1 < LAYERS) ? (l + 1) : 0;  // unused when writeU=0
    k_layer<<<NLB, 640, 0, stream>>>(uin, hcb, uo, ea_s, src_s, off, t, l,
                                     W1 + (size_t)l * DIM * HID, b1 + (size_t)l * HID,
                                     g1 + (size_t)l * HID, be1 + (size_t)l * HID,
                                     W2 + (size_t)l * HID * DIM, b2 + (size_t)l * DIM,
                                     ln_g + (size_t)nxt * DIM, ln_b + (size_t)nxt * DIM,
                                     (l > 0) ? 1 : 0, (l < LAYERS - 1) ? 1 : 0);
  }

  k_final<<<(N_NODES + 3) / 4, 256, 0, stream>>>(hcb, ln_g, ln_b, W_out, b_out, out);
}

// Round 12
// 925.277 us; speedup vs baseline: 1.8493x; 1.0001x over previous
//
#include <hip/hip_runtime.h>
#include <hip/hip_cooperative_groups.h>

namespace cg = cooperative_groups;

#define N_NODES 10000
#define N_EDGES 160000
#define NUM_FEAT 14
#define DIM 64
#define HID 128
#define LAYERS 28

#define NPB 20
#define NLB (N_NODES / NPB)  // 500 blocks, exact
#define TPB 640              // 10 waves

// async global->LDS, 16B/lane: gsrc per-lane (base + lane*4 floats), lds_base
// wave-uniform; HW writes lds_base + lane*16.
__device__ __forceinline__ void stage16(const float* gsrc, float* lds_base) {
  __builtin_amdgcn_global_load_lds(
      (const __attribute__((address_space(1))) void*)gsrc,
      (__attribute__((address_space(3))) void*)lds_base, 16, 0, 0);
}

// ---------------- CSR build (prologue) ----------------

__global__ __launch_bounds__(256) void k_hist(const int* __restrict__ dst, int* __restrict__ cur) {
  int e = blockIdx.x * 256 + threadIdx.x;
  if (e < N_EDGES) atomicAdd(&cur[dst[e]], 1);
}

__global__ __launch_bounds__(256) void k_scan(int* __restrict__ cur, int* __restrict__ off) {
  __shared__ int part[256];
  int t = threadIdx.x;
  const int CH = 40;
  int base = t * CH;
  int s = 0;
  for (int i = 0; i < CH; i++) {
    int idx = base + i;
    if (idx < N_NODES) s += cur[idx];
  }
  part[t] = s;
  __syncthreads();
  for (int ofs = 1; ofs < 256; ofs <<= 1) {
    int tmp = (t >= ofs) ? part[t - ofs] : 0;
    __syncthreads();
    part[t] += tmp;
    __syncthreads();
  }
  int run = part[t] - s;
  for (int i = 0; i < CH; i++) {
    int idx = base + i;
    if (idx < N_NODES) {
      int d = cur[idx];
      off[idx] = run;
      cur[idx] = run;
      run += d;
    }
  }
  if (t == 255) off[N_NODES] = part[255];
}

__global__ __launch_bounds__(256) void k_scatter(const int* __restrict__ dst, int* __restrict__ cur,
                                                 int* __restrict__ eids) {
  int e = blockIdx.x * 256 + threadIdx.x;
  if (e < N_EDGES) {
    int p = atomicAdd(&cur[dst[e]], 1);
    eids[p] = e;
  }
}

// wave-per-node bitonic sort by edge id, then gather src and write the
// precomputed edge embedding ea_s[slot][f] = b_edge[f] + eattr[e]@W_edge[:,f].
__global__ __launch_bounds__(256) void k_sortgather(
    const int* __restrict__ off, const int* __restrict__ eids,
    const int* __restrict__ src, const float4* __restrict__ eattr,
    const float* __restrict__ W_edge, const float* __restrict__ b_edge,
    int* __restrict__ src_s, float4* __restrict__ eattr_s, float* __restrict__ ea_s) {
  int node = blockIdx.x * 4 + (threadIdx.x >> 6);
  int lane = threadIdx.x & 63;
  if (node >= N_NODES) return;
  float we0 = W_edge[lane], we1 = W_edge[64 + lane], we2 = W_edge[128 + lane],
        we3 = W_edge[192 + lane];
  float be = b_edge[lane];
  int a = off[node];
  int d = off[node + 1] - a;
  if (d <= 64) {
    int key = (lane < d) ? eids[a + lane] : 0x7fffffff;
#pragma unroll
    for (int k = 2; k <= 64; k <<= 1) {
      for (int j = k >> 1; j > 0; j >>= 1) {
        int p = __shfl_xor(key, j);
        bool dirUp = ((lane & k) == 0);
        bool isLower = ((lane & j) == 0);
        key = ((isLower == dirUp) ? min(key, p) : max(key, p));
      }
    }
    float4 ev = make_float4(0.f, 0.f, 0.f, 0.f);
    if (lane < d) {
      src_s[a + lane] = src[key];
      ev = eattr[key];
    }
    for (int j = 0; j < d; j++) {
      float ex = __shfl(ev.x, j), ey = __shfl(ev.y, j),
            ez = __shfl(ev.z, j), ew = __shfl(ev.w, j);
      ea_s[(size_t)(a + j) * 64 + lane] =
          be + ex * we0 + ey * we1 + ez * we2 + ew * we3;
    }
  } else {
    for (int i = lane; i < d; i += 64) {
      int e = eids[a + i];
      int r = 0;
      for (int j = 0; j < d; j++) r += (eids[a + j] < e) ? 1 : 0;
      src_s[a + r] = src[e];
      eattr_s[a + r] = eattr[e];
    }
    for (int j = 0; j < d; j++) {
      float4 e4 = eattr_s[a + j];
      ea_s[(size_t)(a + j) * 64 + lane] =
          be + e4.x * we0 + e4.y * we1 + e4.z * we2 + e4.w * we3;
    }
  }
}

// ---------------- node encoder (fallback path) ----------------

__global__ __launch_bounds__(256) void k_enc(const float* __restrict__ x, const float* __restrict__ Wn,
                                             const float* __restrict__ bn, float* __restrict__ hc,
                                             float* __restrict__ u) {
  int gid = blockIdx.x * 256 + threadIdx.x;
  if (gid >= N_NODES * DIM) return;
  int n = gid >> 6, j = gid & 63;
  float acc = bn[j];
#pragma unroll
  for (int k = 0; k < NUM_FEAT; k++) acc += x[n * NUM_FEAT + k] * Wn[k * DIM + j];
  hc[gid] = acc;
  u[gid] = acc;
}

// ---------------- persistent cooperative kernel: enc + 28 layers + final ----------------
// 500 blocks x 640 threads (10 waves). LDS = 32+32+10 = 74KB -> 2 blocks/CU with
// 12KB margin (R11's 79KB had ~0 margin -> coop launch rejected -> zero output).
// Wave wv owns nodes nbase+2wv, +2wv+1 for the whole network; residual hc lives
// in 2 registers/thread. sHZ is a per-wave union: h (first 128 slots) during
// GEMM1, z (256 slots) after -- same-wave data dependency orders the overwrite.
// Edge loop = R10's proven per-node batch-8 max-free softmax.

__global__ __launch_bounds__(TPB, 5) void k_all(
    const float* __restrict__ x,
    const float* __restrict__ W_node, const float* __restrict__ b_node,
    const float* __restrict__ t,
    const float* __restrict__ W1a, const float* __restrict__ b1a,
    const float* __restrict__ g1a, const float* __restrict__ be1a,
    const float* __restrict__ W2a, const float* __restrict__ b2a,
    const float* __restrict__ ln_g, const float* __restrict__ ln_b,
    const float* __restrict__ W_out, const float* __restrict__ b_out,
    float* __restrict__ out,
    const float* __restrict__ ea_s, const int* __restrict__ src_s,
    const int* __restrict__ off,
    float* uA, float* uB) {
  cg::grid_group grid = cg::this_grid();

  __shared__ float sW1[64 * 128];   // 32KB [k][j]
  __shared__ float sW2[128 * 64];   // 32KB [k][i]
  __shared__ float sHZ[10][256];    // 10KB union: h interleaved [0..127], z [0..255]

  const int tid = threadIdx.x;
  const int lane = tid & 63;
  const int wv = tid >> 6;  // 0..9
  const int nbase = blockIdx.x * NPB;
  const int gn0 = __builtin_amdgcn_readfirstlane(nbase + wv * 2);
  const int gn1 = gn0 + 1;

  // ---- node encoder for own 2 nodes (x rows wave-uniform -> s_load) ----
  {
    float wn[NUM_FEAT];
#pragma unroll
    for (int f = 0; f < NUM_FEAT; f++) wn[f] = W_node[f * 64 + lane];
    float bn = b_node[lane];
    float a0 = bn, a1 = bn;
#pragma unroll
    for (int f = 0; f < NUM_FEAT; f++) {
      a0 = fmaf(x[gn0 * NUM_FEAT + f], wn[f], a0);
      a1 = fmaf(x[gn1 * NUM_FEAT + f], wn[f], a1);
    }
    uA[(gn0 << 6) + lane] = a0;
    uA[(gn1 << 6) + lane] = a1;
  }
  grid.sync();  // uA (enc) visible device-wide

  float hc0 = 0.f, hc1 = 0.f;  // residual stream in registers for all layers

  for (int l = 0; l < LAYERS; l++) {
    const float* uin = (l & 1) ? uB : uA;
    float* uout = (l & 1) ? uA : uB;
    const float* W1 = W1a + (size_t)l * 64 * 128;
    const float* W2 = W2a + (size_t)l * 128 * 64;
    const float* b1 = b1a + (size_t)l * 128;
    const float* g1 = g1a + (size_t)l * 128;
    const float* be1 = be1a + (size_t)l * 128;
    const float* b2 = b2a + (size_t)l * 64;

    // ---- stage weights (fire-and-forget; drained by the barrier below) ----
    for (int c = wv; c < 32; c += 10) {
      stage16(W1 + c * 256 + lane * 4, sW1 + c * 256);
      stage16(W2 + c * 256 + lane * 4, sW2 + c * 256);
    }

    // ---- edge aggregation: per-node batch-8 loop (R10-proven), max-free ----
    {
      float tv = t[l];
      float hpair[2];
#pragma unroll
      for (int q = 0; q < 2; q++) {
        int gn = (q == 0) ? gn0 : gn1;             // scalar
        int a = off[gn], d = off[gn + 1] - a;      // scalar
        float un = uin[(gn << 6) + lane];
        float s0 = 0.f, s1 = 0.f, ac0 = 0.f, ac1 = 0.f;
        int i = 0;
        for (; i + 8 <= d; i += 8) {
          float uv[8], ev[8];
#pragma unroll
          for (int j = 0; j < 8; j++) {
            int sn = src_s[a + i + j];                      // s_load
            uv[j] = uin[(sn << 6) + lane];                  // sgpr-base gather
            ev[j] = ea_s[(size_t)(a + i + j) * 64 + lane];  // coalesced stream
          }
#pragma unroll
          for (int j = 0; j < 8; j++) {
            float msg = fmaxf(uv[j] + ev[j], 0.f) + 1e-7f;
            float e = __expf(msg * tv);
            if (j & 1) { s1 += e; ac1 = fmaf(e, msg, ac1); }
            else       { s0 += e; ac0 = fmaf(e, msg, ac0); }
          }
        }
        for (; i < d; i++) {
          int sn = src_s[a + i];
          float msg = fmaxf(uin[(sn << 6) + lane] + ea_s[(size_t)(a + i) * 64 + lane],
                            0.f) + 1e-7f;
          float e = __expf(msg * tv);
          s0 += e;
          ac0 = fmaf(e, msg, ac0);
        }
        hpair[q] = (ac0 + ac1) / (s0 + s1 + 1e-16f) + un;
      }
      *((float2*)&sHZ[wv][lane * 2]) = make_float2(hpair[0], hpair[1]);
    }
    __syncthreads();  // drains global_load_lds (vmcnt); sHZ is wave-private

    // ---- GEMM1: cols j0=2*lane, j0+1; 2 nodes ----
    int j0 = 2 * lane;
    float2 b1v = *((const float2*)&b1[j0]);
    float a00 = b1v.x, a01 = b1v.y, a10 = b1v.x, a11 = b1v.y;
#pragma unroll 8
    for (int k = 0; k < 64; k++) {
      float2 hp = *((float2*)&sHZ[wv][k * 2]);
      float2 wp = *((float2*)&sW1[k * 128 + j0]);
      a00 += hp.x * wp.x; a01 += hp.x * wp.y;
      a10 += hp.y * wp.x; a11 += hp.y * wp.y;
    }

    // ---- LN1 (over 128) via shfl; z overwrites sHZ (same wave, dep-ordered) ----
    {
      float2 gv = *((const float2*)&g1[j0]);
      float2 bev = *((const float2*)&be1[j0]);
      float s0 = a00 + a01, q0 = a00 * a00 + a01 * a01;
      float s1 = a10 + a11, q1 = a10 * a10 + a11 * a11;
#pragma unroll
      for (int o = 32; o; o >>= 1) {
        s0 += __shfl_xor(s0, o); q0 += __shfl_xor(q0, o);
        s1 += __shfl_xor(s1, o); q1 += __shfl_xor(q1, o);
      }
      float mu0 = s0 * (1.f / 128.f), mu1 = s1 * (1.f / 128.f);
      float rs0 = rsqrtf(q0 * (1.f / 128.f) - mu0 * mu0 + 1e-5f);
      float rs1 = rsqrtf(q1 * (1.f / 128.f) - mu1 * mu1 + 1e-5f);
      float4 zv;
      zv.x = fmaxf((a00 - mu0) * rs0 * gv.x + bev.x, 0.f);
      zv.y = fmaxf((a10 - mu1) * rs1 * gv.x + bev.x, 0.f);
      zv.z = fmaxf((a01 - mu0) * rs0 * gv.y + bev.y, 0.f);
      zv.w = fmaxf((a11 - mu1) * rs1 * gv.y + bev.y, 0.f);
      *((float4*)&sHZ[wv][4 * lane]) = zv;
    }

    // ---- GEMM2: col i=lane; 2 nodes ----
    float bo = b2[lane];
    float o0 = bo, o1 = bo;
#pragma unroll 8
    for (int k = 0; k < 128; k++) {
      float2 zp = *((float2*)&sHZ[wv][k * 2]);
      float wv2 = sW2[k * 64 + lane];
      o0 += zp.x * wv2;
      o1 += zp.y * wv2;
    }

    // ---- residual in registers ----
    hc0 += o0;
    hc1 += o1;

    // ---- next-layer pre-LN: uout = relu(LN(hc, ln_g[l+1], ln_b[l+1])) ----
    if (l < LAYERS - 1) {
      float lg_ = ln_g[(l + 1) * 64 + lane], lb_ = ln_b[(l + 1) * 64 + lane];
      float s0 = hc0, q0 = hc0 * hc0;
      float s1 = hc1, q1 = hc1 * hc1;
#pragma unroll
      for (int o = 32; o; o >>= 1) {
        s0 += __shfl_xor(s0, o); q0 += __shfl_xor(q0, o);
        s1 += __shfl_xor(s1, o); q1 += __shfl_xor(q1, o);
      }
      float mu0 = s0 * (1.f / 64.f), mu1 = s1 * (1.f / 64.f);
      float rs0 = rsqrtf(q0 * (1.f / 64.f) - mu0 * mu0 + 1e-5f);
      float rs1 = rsqrtf(q1 * (1.f / 64.f) - mu1 * mu1 + 1e-5f);
      uout[(gn0 << 6) + lane] = fmaxf((hc0 - mu0) * rs0 * lg_ + lb_, 0.f);
      uout[(gn1 << 6) + lane] = fmaxf((hc1 - mu1) * rs1 * lg_ + lb_, 0.f);
      grid.sync();  // uout visible device-wide before next layer reads it
    }
  }

  // ---- final: out = relu(LN(hc, ln_g[0], ln_b[0])) @ W_out + b_out ----
  __syncthreads();  // all waves done reading sW1/sW2 (layer-27 GEMMs)
  for (int c = wv; c < 16; c += 10) {
    stage16(W_out + c * 256 + lane * 4, sW1 + c * 256);
  }
  {
    float lg_ = ln_g[lane], lb_ = ln_b[lane];
    float s0 = hc0, q0 = hc0 * hc0;
    float s1 = hc1, q1 = hc1 * hc1;
#pragma unroll
    for (int o = 32; o; o >>= 1) {
      s0 += __shfl_xor(s0, o); q0 += __shfl_xor(q0, o);
      s1 += __shfl_xor(s1, o); q1 += __shfl_xor(q1, o);
    }
    float mu0 = s0 * (1.f / 64.f), mu1 = s1 * (1.f / 64.f);
    float rs0 = rsqrtf(q0 * (1.f / 64.f) - mu0 * mu0 + 1e-5f);
    float rs1 = rsqrtf(q1 * (1.f / 64.f) - mu1 * mu1 + 1e-5f);
    float z0 = fmaxf((hc0 - mu0) * rs0 * lg_ + lb_, 0.f);
    float z1 = fmaxf((hc1 - mu1) * rs1 * lg_ + lb_, 0.f);
    *((float2*)&sHZ[wv][lane * 2]) = make_float2(z0, z1);
  }
  __syncthreads();  // drain W_out staging
  {
    float bo = b_out[lane];
    float o0 = bo, o1 = bo;
#pragma unroll 8
    for (int k = 0; k < 64; k++) {
      float2 zp = *((float2*)&sHZ[wv][k * 2]);
      float wv2 = sW1[k * 64 + lane];
      o0 += zp.x * wv2;
      o1 += zp.y * wv2;
    }
    out[(gn0 << 6) + lane] = o0;
    out[(gn1 << 6) + lane] = o1;
  }
}

// ---------------- fallback split path (R10, proven) ----------------

__global__ __launch_bounds__(640, 5) void k_layer(
    const float* __restrict__ uin, float* __restrict__ hc, float* __restrict__ uout,
    const float* __restrict__ ea_s, const int* __restrict__ src_s,
    const int* __restrict__ off, const float* __restrict__ tptr, int layer,
    const float* __restrict__ W1, const float* __restrict__ b1,
    const float* __restrict__ g1, const float* __restrict__ be1,
    const float* __restrict__ W2, const float* __restrict__ b2,
    const float* __restrict__ lng, const float* __restrict__ lnb,
    int addRes, int writeU) {
  __shared__ float sW1[64 * 128];
  __shared__ float sW2[128 * 64];
  __shared__ float sHZ[10][256];

  const int tid = threadIdx.x;
  const int lane = tid & 63;
  const int wv = tid >> 6;
  const int nbase = blockIdx.x * NPB;

  for (int c = wv; c < 32; c += 10) {
    stage16(W1 + c * 256 + lane * 4, sW1 + c * 256);
    stage16(W2 + c * 256 + lane * 4, sW2 + c * 256);
  }

  {
    float tv = tptr[layer];
    float hpair[2];
#pragma unroll
    for (int q = 0; q < 2; q++) {
      int gn = __builtin_amdgcn_readfirstlane(nbase + wv * 2 + q);
      int a = off[gn], d = off[gn + 1] - a;
      float un = uin[(gn << 6) + lane];
      float s0 = 0.f, s1 = 0.f, ac0 = 0.f, ac1 = 0.f;
      int i = 0;
      for (; i + 8 <= d; i += 8) {
        float uv[8], ev[8];
#pragma unroll
        for (int j = 0; j < 8; j++) {
          int sn = src_s[a + i + j];
          uv[j] = uin[(sn << 6) + lane];
          ev[j] = ea_s[(size_t)(a + i + j) * 64 + lane];
        }
#pragma unroll
        for (int j = 0; j < 8; j++) {
          float msg = fmaxf(uv[j] + ev[j], 0.f) + 1e-7f;
          float e = __expf(msg * tv);
          if (j & 1) { s1 += e; ac1 = fmaf(e, msg, ac1); }
          else       { s0 += e; ac0 = fmaf(e, msg, ac0); }
        }
      }
      for (; i < d; i++) {
        int sn = src_s[a + i];
        float msg = fmaxf(uin[(sn << 6) + lane] + ea_s[(size_t)(a + i) * 64 + lane],
                          0.f) + 1e-7f;
        float e = __expf(msg * tv);
        s0 += e;
        ac0 = fmaf(e, msg, ac0);
      }
      hpair[q] = (ac0 + ac1) / (s0 + s1 + 1e-16f) + un;
    }
    *((float2*)&sHZ[wv][lane * 2]) = make_float2(hpair[0], hpair[1]);
  }
  __syncthreads();

  const int gn0 = nbase + wv * 2;
  const int gn1 = gn0 + 1;

  int j0 = 2 * lane;
  float2 b1v = *((const float2*)&b1[j0]);
  float a00 = b1v.x, a01 = b1v.y, a10 = b1v.x, a11 = b1v.y;
#pragma unroll 8
  for (int k = 0; k < 64; k++) {
    float2 hp = *((float2*)&sHZ[wv][k * 2]);
    float2 wp = *((float2*)&sW1[k * 128 + j0]);
    a00 += hp.x * wp.x; a01 += hp.x * wp.y;
    a10 += hp.y * wp.x; a11 += hp.y * wp.y;
  }

  {
    float2 gv = *((const float2*)&g1[j0]);
    float2 bev = *((const float2*)&be1[j0]);
    float s0 = a00 + a01, q0 = a00 * a00 + a01 * a01;
    float s1 = a10 + a11, q1 = a10 * a10 + a11 * a11;
#pragma unroll
    for (int o = 32; o; o >>= 1) {
      s0 += __shfl_xor(s0, o); q0 += __shfl_xor(q0, o);
      s1 += __shfl_xor(s1, o); q1 += __shfl_xor(q1, o);
    }
    float mu0 = s0 * (1.f / 128.f), mu1 = s1 * (1.f / 128.f);
    float rs0 = rsqrtf(q0 * (1.f / 128.f) - mu0 * mu0 + 1e-5f);
    float rs1 = rsqrtf(q1 * (1.f / 128.f) - mu1 * mu1 + 1e-5f);
    float4 zv;
    zv.x = fmaxf((a00 - mu0) * rs0 * gv.x + bev.x, 0.f);
    zv.y = fmaxf((a10 - mu1) * rs1 * gv.x + bev.x, 0.f);
    zv.z = fmaxf((a01 - mu0) * rs0 * gv.y + bev.y, 0.f);
    zv.w = fmaxf((a11 - mu1) * rs1 * gv.y + bev.y, 0.f);
    *((float4*)&sHZ[wv][4 * lane]) = zv;
  }

  float bo = b2[lane];
  float o0 = bo, o1 = bo;
#pragma unroll 8
  for (int k = 0; k < 128; k++) {
    float2 zp = *((float2*)&sHZ[wv][k * 2]);
    float wv2 = sW2[k * 64 + lane];
    o0 += zp.x * wv2;
    o1 += zp.y * wv2;
  }

  float r0 = addRes ? hc[gn0 * 64 + lane] : 0.f;
  float r1 = addRes ? hc[gn1 * 64 + lane] : 0.f;
  float hcn0 = o0 + r0, hcn1 = o1 + r1;
  hc[gn0 * 64 + lane] = hcn0;
  hc[gn1 * 64 + lane] = hcn1;

  if (writeU) {
    float lg_ = lng[lane], lb_ = lnb[lane];
    float s0 = hcn0, q0 = hcn0 * hcn0;
    float s1 = hcn1, q1 = hcn1 * hcn1;
#pragma unroll
    for (int o = 32; o; o >>= 1) {
      s0 += __shfl_xor(s0, o); q0 += __shfl_xor(q0, o);
      s1 += __shfl_xor(s1, o); q1 += __shfl_xor(q1, o);
    }
    float mu0 = s0 * (1.f / 64.f), mu1 = s1 * (1.f / 64.f);
    float rs0 = rsqrtf(q0 * (1.f / 64.f) - mu0 * mu0 + 1e-5f);
    float rs1 = rsqrtf(q1 * (1.f / 64.f) - mu1 * mu1 + 1e-5f);
    uout[gn0 * 64 + lane] = fmaxf((hcn0 - mu0) * rs0 * lg_ + lb_, 0.f);
    uout[gn1 * 64 + lane] = fmaxf((hcn1 - mu1) * rs1 * lg_ + lb_, 0.f);
  }
}

__global__ __launch_bounds__(256) void k_final(const float* __restrict__ hc, const float* __restrict__ g,
                                               const float* __restrict__ bptr, const float* __restrict__ Wout,
                                               const float* __restrict__ bout, float* __restrict__ out) {
  __shared__ float sW[DIM * DIM];
  int tid = threadIdx.x;
  for (int i = tid; i < 1024; i += 256) ((float4*)sW)[i] = ((const float4*)Wout)[i];
  __syncthreads();
  int lane = tid & 63, w = tid >> 6;
  int n = blockIdx.x * 4 + w;
  if (n >= N_NODES) return;
  float v = hc[n * 64 + lane];
  float s = v, q = v * v;
#pragma unroll
  for (int o = 32; o; o >>= 1) { s += __shfl_xor(s, o); q += __shfl_xor(q, o); }
  float mu = s * (1.f / 64.f);
  float var = q * (1.f / 64.f) - mu * mu;
  float rs = rsqrtf(var + 1e-5f);
  float z = fmaxf((v - mu) * rs * g[lane] + bptr[lane], 0.f);
  float acc = bout[lane];
  for (int k = 0; k < 64; k++) {
    float zk = __shfl(z, k);
    acc += zk * sW[k * 64 + lane];
  }
  out[n * 64 + lane] = acc;
}

// ---------------- host ----------------

extern "C" void kernel_launch(void* const* d_in, const int* in_sizes, int n_in,
                              void* d_out, int out_size, void* d_ws, size_t ws_size,
                              hipStream_t stream) {
  const float* x        = (const float*)d_in[0];
  const float* eattr    = (const float*)d_in[1];
  const int*   src      = (const int*)d_in[2];
  const int*   dst      = (const int*)d_in[3];
  const float* W_node   = (const float*)d_in[4];
  const float* b_node   = (const float*)d_in[5];
  const float* W_edge   = (const float*)d_in[6];
  const float* b_edge   = (const float*)d_in[7];
  const float* t        = (const float*)d_in[8];
  const float* W1       = (const float*)d_in[9];
  const float* b1       = (const float*)d_in[10];
  const float* g1       = (const float*)d_in[11];
  const float* be1      = (const float*)d_in[12];
  const float* W2       = (const float*)d_in[13];
  const float* b2       = (const float*)d_in[14];
  const float* ln_g     = (const float*)d_in[15];
  const float* ln_b     = (const float*)d_in[16];
  const float* W_out    = (const float*)d_in[17];
  const float* b_out    = (const float*)d_in[18];
  float* out = (float*)d_out;

  char* w = (char*)d_ws;
  float* uA      = (float*)w;  w += (size_t)N_NODES * 64 * 4;
  float* uB      = (float*)w;  w += (size_t)N_NODES * 64 * 4;
  float* hcb     = (float*)w;  w += (size_t)N_NODES * 64 * 4;
  int* off       = (int*)w;    w += (size_t)(N_NODES + 1) * 4;
  int* cur       = (int*)w;    w += (size_t)N_NODES * 4;
  int* eids      = (int*)w;    w += (size_t)N_EDGES * 4;
  int* src_s     = (int*)w;    w += (size_t)N_EDGES * 4;
  float4* eattr_s = (float4*)w; w += (size_t)N_EDGES * 16;
  float* ea_s    = (float*)w;  w += (size_t)N_EDGES * 64 * 4;

  hipMemsetAsync(cur, 0, (size_t)N_NODES * 4, stream);
  k_hist<<<(N_EDGES + 255) / 256, 256, 0, stream>>>(dst, cur);
  k_scan<<<1, 256, 0, stream>>>(cur, off);
  k_scatter<<<(N_EDGES + 255) / 256, 256, 0, stream>>>(dst, cur, eids);
  k_sortgather<<<(N_NODES + 3) / 4, 256, 0, stream>>>(off, eids, src, (const float4*)eattr,
                                                      W_edge, b_edge, src_s, eattr_s, ea_s);

  // choose coop (persistent) path only if the grid is guaranteed co-resident
  int maxBlocksPerCU = 0;
  hipError_t qerr = hipOccupancyMaxActiveBlocksPerMultiprocessor(&maxBlocksPerCU, k_all, TPB, 0);
  int dev = 0, nCU = 0;
  hipGetDevice(&dev);
  hipDeviceGetAttribute(&nCU, hipDeviceAttributeMultiprocessorCount, dev);
  bool coop_ok = (qerr == hipSuccess) && ((long)maxBlocksPerCU * (long)nCU >= (long)NLB);

  hipError_t lerr = hipErrorUnknown;
  if (coop_ok) {
    void* args[] = {
        (void*)&x, (void*)&W_node, (void*)&b_node, (void*)&t,
        (void*)&W1, (void*)&b1, (void*)&g1, (void*)&be1, (void*)&W2, (void*)&b2,
        (void*)&ln_g, (void*)&ln_b, (void*)&W_out, (void*)&b_out,
        (void*)&out, (void*)&ea_s, (void*)&src_s, (void*)&off,
        (void*)&uA, (void*)&uB};
    lerr = hipLaunchCooperativeKernel((const void*)k_all, dim3(NLB), dim3(TPB), args, 0, stream);
  }
  if (!coop_ok || lerr != hipSuccess) {
    // fallback: proven R10 split path
    k_enc<<<(N_NODES * 64 + 255) / 256, 256, 0, stream>>>(x, W_node, b_node, hcb, uA);
    for (int l = 0; l < LAYERS; l++) {
      const float* uin = (l & 1) ? uB : uA;
      float* uo        = (l & 1) ? uA : uB;
      int nxt = (l + 1 < LAYERS) ? (l + 1) : 0;
      k_layer<<<NLB, 640, 0, stream>>>(uin, hcb, uo, ea_s, src_s, off, t, l,
                                       W1 + (size_t)l * DIM * HID, b1 + (size_t)l * HID,
                                       g1 + (size_t)l * HID, be1 + (size_t)l * HID,
                                       W2 + (size_t)l * HID * DIM, b2 + (size_t)l * DIM,
                                       ln_g + (size_t)nxt * DIM, ln_b + (size_t)nxt * DIM,
                                       (l > 0) ? 1 : 0, (l < LAYERS - 1) ? 1 : 0);
    }
    k_final<<<(N_NODES + 3) / 4, 256, 0, stream>>>(hcb, ln_g, ln_b, W_out, b_out, out);
  }
}